// Round 1
// baseline (1427.352 us; speedup 1.0000x reference)
//
#include <hip/hip_runtime.h>
#include <hip/hip_bf16.h>

#define HEADS 8
#define HID 16
#define F1 128    // HEADS*HID
#define OUTD 64
#define INIT_U 0x007FFFFFu   // fmap(-inf)

// monotone float->uint map for atomicMax on floats
__device__ __forceinline__ unsigned fmap(float f) {
  int i = __float_as_int(f);
  return (unsigned)(i ^ ((i >> 31) | 0x80000000));
}
__device__ __forceinline__ float finv(unsigned u) {
  int i = (u & 0x80000000u) ? (int)(u ^ 0x80000000u) : ~(int)u;
  return __int_as_float(i);
}

__global__ void k_init1(float* __restrict__ out1, unsigned* __restrict__ m1,
                        float* __restrict__ s1, const float* __restrict__ b1, int N) {
  int idx = blockIdx.x * blockDim.x + threadIdx.x;
  if (idx < N * F1) out1[idx] = b1[idx & (F1 - 1)];
  if (idx < N * HEADS) { m1[idx] = INIT_U; s1[idx] = 0.f; }
}

// h1 = x @ W1  (+ per-head attention dots)
__global__ void k_gemm1(const float* __restrict__ x, const float* __restrict__ W1,
                        const float* __restrict__ as, const float* __restrict__ ad,
                        float* __restrict__ h1, float* __restrict__ a_src,
                        float* __restrict__ a_dst, int N) {
  __shared__ float xs[2][F1];
  __shared__ float hs[2][F1];
  int l = threadIdx.x >> 7, c = threadIdx.x & 127;
  int row = blockIdx.x * 2 + l;
  bool act = row < N;
  xs[l][c] = act ? x[(size_t)row * F1 + c] : 0.f;
  __syncthreads();
  float acc = 0.f;
#pragma unroll 8
  for (int k = 0; k < F1; ++k) acc = fmaf(xs[l][k], W1[k * F1 + c], acc);
  if (act) h1[(size_t)row * F1 + c] = acc;
  hs[l][c] = acc;
  __syncthreads();
  if (act && c < HEADS) {
    float ss = 0.f, sd = 0.f;
#pragma unroll
    for (int j = 0; j < HID; ++j) {
      float v = hs[l][c * HID + j];
      ss = fmaf(v, as[c * HID + j], ss);
      sd = fmaf(v, ad[c * HID + j], sd);
    }
    a_src[row * HEADS + c] = ss;
    a_dst[row * HEADS + c] = sd;
  }
}

// pass 1: e = leaky_relu(a_src[s]+a_dst[d]); atomicMax per dst
__global__ void k_edge1_a(const int* __restrict__ ei, int E, int N,
                          const float* __restrict__ a_src, const float* __restrict__ a_dst,
                          float* __restrict__ e1, unsigned* __restrict__ m1) {
  int e = blockIdx.x * blockDim.x + threadIdx.x;
  int ET = E + N;
  if (e >= ET) return;
  int s = e < E ? ei[e] : e - E;
  int d = e < E ? ei[E + e] : e - E;
#pragma unroll
  for (int h = 0; h < HEADS; ++h) {
    float v = a_src[s * HEADS + h] + a_dst[d * HEADS + h];
    v = v >= 0.f ? v : 0.2f * v;
    e1[(size_t)e * HEADS + h] = v;
    atomicMax(&m1[d * HEADS + h], fmap(v));
  }
}

// pass 2: expe = exp(e - m[d]); atomicAdd denom
__global__ void k_edge1_b(const int* __restrict__ ei, int E, int N,
                          const unsigned* __restrict__ m1, float* __restrict__ e1,
                          float* __restrict__ s1) {
  int e = blockIdx.x * blockDim.x + threadIdx.x;
  int ET = E + N;
  if (e >= ET) return;
  int d = e < E ? ei[E + e] : e - E;
#pragma unroll
  for (int h = 0; h < HEADS; ++h) {
    float ex = __expf(e1[(size_t)e * HEADS + h] - finv(m1[d * HEADS + h]));
    e1[(size_t)e * HEADS + h] = ex;
    atomicAdd(&s1[d * HEADS + h], ex);
  }
}

// pass 3: out1[d] += h1[s] * alpha   (128 threads per edge)
__global__ void k_edge1_c(const int* __restrict__ ei, int E, int N,
                          const float* __restrict__ h1, const float* __restrict__ e1,
                          const float* __restrict__ s1, float* __restrict__ out1) {
  long long t = (long long)blockIdx.x * blockDim.x + threadIdx.x;
  int e = (int)(t >> 7);
  int c = (int)(t & 127);
  int ET = E + N;
  if (e >= ET) return;
  int s = e < E ? ei[e] : e - E;
  int d = e < E ? ei[E + e] : e - E;
  int h = c >> 4;
  float alpha = e1[(size_t)e * HEADS + h] / (s1[d * HEADS + h] + 1e-16f);
  atomicAdd(&out1[(size_t)d * F1 + c], h1[(size_t)s * F1 + c] * alpha);
}

__global__ void k_init2(float* __restrict__ out, const float* __restrict__ b2,
                        unsigned* __restrict__ m2, float* __restrict__ s2, int N) {
  int idx = blockIdx.x * blockDim.x + threadIdx.x;
  if (idx < N * OUTD) out[idx] = b2[idx & (OUTD - 1)];
  if (idx < N) { m2[idx] = INIT_U; s2[idx] = 0.f; }
}

// h2 = elu(out1) @ W2 (+ scalar attention dots via wave reduce). 4 waves/block, 1 row/wave.
__global__ void k_gemm2(const float* __restrict__ out1, const float* __restrict__ W2,
                        const float* __restrict__ as2, const float* __restrict__ ad2,
                        float* __restrict__ h2, float* __restrict__ a_src2,
                        float* __restrict__ a_dst2, int N) {
  __shared__ float rs[4][F1];
  int w = threadIdx.x >> 6, lane = threadIdx.x & 63;
  int row = blockIdx.x * 4 + w;
  bool act = row < N;
  if (act) {
#pragma unroll
    for (int i = lane; i < F1; i += 64) {
      float v = out1[(size_t)row * F1 + i];
      rs[w][i] = v > 0.f ? v : __expf(v) - 1.f;
    }
    float acc = 0.f;
#pragma unroll 8
    for (int k = 0; k < F1; ++k) acc = fmaf(rs[w][k], W2[k * OUTD + lane], acc);
    h2[(size_t)row * OUTD + lane] = acc;
    float ps = acc * as2[lane], pd = acc * ad2[lane];
#pragma unroll
    for (int off = 32; off > 0; off >>= 1) {
      ps += __shfl_down(ps, off);
      pd += __shfl_down(pd, off);
    }
    if (lane == 0) { a_src2[row] = ps; a_dst2[row] = pd; }
  }
}

__global__ void k_edge2_a(const int* __restrict__ ei, int E, int N,
                          const float* __restrict__ a_src2, const float* __restrict__ a_dst2,
                          float* __restrict__ e2, unsigned* __restrict__ m2) {
  int e = blockIdx.x * blockDim.x + threadIdx.x;
  int ET = E + N;
  if (e >= ET) return;
  int s = e < E ? ei[e] : e - E;
  int d = e < E ? ei[E + e] : e - E;
  float v = a_src2[s] + a_dst2[d];
  v = v >= 0.f ? v : 0.2f * v;
  e2[e] = v;
  atomicMax(&m2[d], fmap(v));
}

__global__ void k_edge2_b(const int* __restrict__ ei, int E, int N,
                          const unsigned* __restrict__ m2, float* __restrict__ e2,
                          float* __restrict__ s2) {
  int e = blockIdx.x * blockDim.x + threadIdx.x;
  int ET = E + N;
  if (e >= ET) return;
  int d = e < E ? ei[E + e] : e - E;
  float ex = __expf(e2[e] - finv(m2[d]));
  e2[e] = ex;
  atomicAdd(&s2[d], ex);
}

// out[d] += h2[s] * alpha  (64 threads per edge)
__global__ void k_edge2_c(const int* __restrict__ ei, int E, int N,
                          const float* __restrict__ h2, const float* __restrict__ e2,
                          const float* __restrict__ s2, float* __restrict__ out) {
  long long t = (long long)blockIdx.x * blockDim.x + threadIdx.x;
  int e = (int)(t >> 6);
  int c = (int)(t & 63);
  int ET = E + N;
  if (e >= ET) return;
  int s = e < E ? ei[e] : e - E;
  int d = e < E ? ei[E + e] : e - E;
  float alpha = e2[e] / (s2[d] + 1e-16f);
  atomicAdd(&out[(size_t)d * OUTD + c], h2[(size_t)s * OUTD + c] * alpha);
}

extern "C" void kernel_launch(void* const* d_in, const int* in_sizes, int n_in,
                              void* d_out, int out_size, void* d_ws, size_t ws_size,
                              hipStream_t stream) {
  const float* x   = (const float*)d_in[0];
  const int*   ei  = (const int*)d_in[1];
  const float* W1  = (const float*)d_in[2];
  const float* as1 = (const float*)d_in[3];
  const float* ad1 = (const float*)d_in[4];
  const float* b1  = (const float*)d_in[5];
  const float* W2  = (const float*)d_in[6];
  const float* as2 = (const float*)d_in[7];
  const float* ad2 = (const float*)d_in[8];
  const float* b2  = (const float*)d_in[9];
  float* out = (float*)d_out;

  int N = in_sizes[0] / F1;
  int E = in_sizes[1] / 2;
  int ET = E + N;

  // workspace layout (layer-2 buffers alias layer-1's dead regions)
  float* ws = (float*)d_ws;
  float* h1     = ws;                               // N*F1
  float* out1   = h1 + (size_t)N * F1;              // N*F1
  float* a_src1 = out1 + (size_t)N * F1;            // N*H
  float* a_dst1 = a_src1 + (size_t)N * HEADS;       // N*H
  unsigned* m1  = (unsigned*)(a_dst1 + (size_t)N * HEADS); // N*H
  float* s1     = (float*)(m1 + (size_t)N * HEADS); // N*H
  float* e1     = s1 + (size_t)N * HEADS;           // ET*H
  // layer-2 aliases (h1 and e1 are dead after k_edge1_c)
  float* h2     = h1;                               // N*OUTD
  float* a_src2 = h1 + (size_t)N * OUTD;            // N
  float* a_dst2 = a_src2 + N;                       // N
  unsigned* m2  = (unsigned*)(a_dst2 + N);          // N
  float* s2     = (float*)(m2 + N);                 // N
  float* e2     = e1;                               // ET

  hipLaunchKernelGGL(k_init1, dim3((N * F1 + 255) / 256), dim3(256), 0, stream,
                     out1, m1, s1, b1, N);
  hipLaunchKernelGGL(k_gemm1, dim3((N + 1) / 2), dim3(256), 0, stream,
                     x, W1, as1, ad1, h1, a_src1, a_dst1, N);
  hipLaunchKernelGGL(k_edge1_a, dim3((ET + 255) / 256), dim3(256), 0, stream,
                     ei, E, N, a_src1, a_dst1, e1, m1);
  hipLaunchKernelGGL(k_edge1_b, dim3((ET + 255) / 256), dim3(256), 0, stream,
                     ei, E, N, m1, e1, s1);
  hipLaunchKernelGGL(k_edge1_c, dim3((ET + 1) / 2), dim3(256), 0, stream,
                     ei, E, N, h1, e1, s1, out1);
  hipLaunchKernelGGL(k_init2, dim3((N * F1 + 255) / 256), dim3(256), 0, stream,
                     out, b2, m2, s2, N);
  hipLaunchKernelGGL(k_gemm2, dim3((N + 3) / 4), dim3(256), 0, stream,
                     out1, W2, as2, ad2, h2, a_src2, a_dst2, N);
  hipLaunchKernelGGL(k_edge2_a, dim3((ET + 255) / 256), dim3(256), 0, stream,
                     ei, E, N, a_src2, a_dst2, e2, m2);
  hipLaunchKernelGGL(k_edge2_b, dim3((ET + 255) / 256), dim3(256), 0, stream,
                     ei, E, N, m2, e2, s2);
  hipLaunchKernelGGL(k_edge2_c, dim3((ET + 3) / 4), dim3(256), 0, stream,
                     ei, E, N, h2, e2, s2, out);
}

// Round 2
// 632.260 us; speedup vs baseline: 2.2575x; 2.2575x over previous
//
#include <hip/hip_runtime.h>
#include <hip/hip_bf16.h>

#define HEADS 8
#define HID 16
#define F1 128    // HEADS*HID
#define OUTD 64
#define SCANB 256

// ---------------- CSR build ----------------

__global__ void k_zero(int* __restrict__ deg, int N) {
  int i = blockIdx.x * blockDim.x + threadIdx.x;
  if (i < N) deg[i] = 0;
}

__global__ void k_count(const int* __restrict__ ei, int E, int N, int* __restrict__ deg) {
  int e = blockIdx.x * blockDim.x + threadIdx.x;
  if (e >= E + N) return;
  int d = e < E ? ei[E + e] : e - E;
  atomicAdd(&deg[d], 1);
}

// block-level inclusive scan of deg -> off[i+1] (pre-block-offset), block sums -> bsum
__global__ void k_scan1(const int* __restrict__ deg, int N, int* __restrict__ off,
                        int* __restrict__ bsum) {
  __shared__ int sm[SCANB];
  int t = threadIdx.x, i = blockIdx.x * SCANB + t;
  int v = i < N ? deg[i] : 0;
  sm[t] = v; __syncthreads();
  for (int o = 1; o < SCANB; o <<= 1) {
    int u = t >= o ? sm[t - o] : 0;
    __syncthreads();
    sm[t] += u;
    __syncthreads();
  }
  if (i < N) off[i + 1] = sm[t];
  if (t == SCANB - 1) bsum[blockIdx.x] = sm[t];
}

// scan the block sums (NB <= 256) -> exclusive block offsets in-place
__global__ void k_scan2(int* __restrict__ bsum, int NB) {
  __shared__ int sm[SCANB];
  int t = threadIdx.x;
  int v = t < NB ? bsum[t] : 0;
  sm[t] = v; __syncthreads();
  for (int o = 1; o < SCANB; o <<= 1) {
    int u = t >= o ? sm[t - o] : 0;
    __syncthreads();
    sm[t] += u;
    __syncthreads();
  }
  if (t < NB) bsum[t] = sm[t] - v;   // exclusive
}

__global__ void k_scan3(int* __restrict__ off, int* __restrict__ cursor,
                        const int* __restrict__ deg, const int* __restrict__ bsum, int N) {
  int i = blockIdx.x * SCANB + threadIdx.x;
  if (i >= N) return;
  int v = off[i + 1] + bsum[blockIdx.x];
  off[i + 1] = v;
  cursor[i] = v - deg[i];
  if (i == 0) off[0] = 0;
}

__global__ void k_fill(const int* __restrict__ ei, int E, int N,
                       int* __restrict__ cursor, int* __restrict__ csr) {
  int e = blockIdx.x * blockDim.x + threadIdx.x;
  if (e >= E + N) return;
  int s = e < E ? ei[e] : e - E;
  int d = e < E ? ei[E + e] : e - E;
  int pos = atomicAdd(&cursor[d], 1);
  csr[pos] = s;
}

// ---------------- layer 1 ----------------

// h1 = x @ W1  (+ per-head attention dots)
__global__ void k_gemm1(const float* __restrict__ x, const float* __restrict__ W1,
                        const float* __restrict__ as, const float* __restrict__ ad,
                        float* __restrict__ h1, float* __restrict__ a_src,
                        float* __restrict__ a_dst, int N) {
  __shared__ float xs[2][F1];
  __shared__ float hs[2][F1];
  int l = threadIdx.x >> 7, c = threadIdx.x & 127;
  int row = blockIdx.x * 2 + l;
  bool act = row < N;
  xs[l][c] = act ? x[(size_t)row * F1 + c] : 0.f;
  __syncthreads();
  float acc = 0.f;
#pragma unroll 8
  for (int k = 0; k < F1; ++k) acc = fmaf(xs[l][k], W1[k * F1 + c], acc);
  if (act) h1[(size_t)row * F1 + c] = acc;
  hs[l][c] = acc;
  __syncthreads();
  if (act && c < HEADS) {
    float ss = 0.f, sd = 0.f;
#pragma unroll
    for (int j = 0; j < HID; ++j) {
      float v = hs[l][c * HID + j];
      ss = fmaf(v, as[c * HID + j], ss);
      sd = fmaf(v, ad[c * HID + j], sd);
    }
    a_src[row * HEADS + c] = ss;
    a_dst[row * HEADS + c] = sd;
  }
}

// fused softmax + aggregate, per destination. 2 dsts / 256-thread block,
// 128 threads per dst (thread c owns channel c, head = c>>4).
__global__ void k_agg1(const int* __restrict__ off, const int* __restrict__ csr,
                       const float* __restrict__ h1, const float* __restrict__ a_src,
                       const float* __restrict__ a_dst, const float* __restrict__ b1,
                       float* __restrict__ out1, int N) {
  int q = threadIdx.x >> 7, c = threadIdx.x & 127, h = c >> 4;
  int d = blockIdx.x * 2 + q;
  if (d >= N) return;
  int beg = off[d], end = off[d + 1];
  float adl = a_dst[d * HEADS + h];
  float m = -1e30f;
  for (int j = beg; j < end; ++j) {
    int s = csr[j];
    float v = a_src[s * HEADS + h] + adl;
    v = v >= 0.f ? v : 0.2f * v;
    m = fmaxf(m, v);
  }
  float sum = 0.f, acc = 0.f;
  for (int j = beg; j < end; ++j) {
    int s = csr[j];
    float v = a_src[s * HEADS + h] + adl;
    v = v >= 0.f ? v : 0.2f * v;
    float p = __expf(v - m);
    sum += p;
    acc = fmaf(p, h1[(size_t)s * F1 + c], acc);
  }
  out1[(size_t)d * F1 + c] = acc / (sum + 1e-16f) + b1[c];
}

// ---------------- layer 2 ----------------

// h2 = elu(out1) @ W2 (+ scalar attention dots via wave reduce). 1 row/wave.
__global__ void k_gemm2(const float* __restrict__ out1, const float* __restrict__ W2,
                        const float* __restrict__ as2, const float* __restrict__ ad2,
                        float* __restrict__ h2, float* __restrict__ a_src2,
                        float* __restrict__ a_dst2, int N) {
  __shared__ float rs[4][F1];
  int w = threadIdx.x >> 6, lane = threadIdx.x & 63;
  int row = blockIdx.x * 4 + w;
  bool act = row < N;
  if (act) {
#pragma unroll
    for (int i = lane; i < F1; i += 64) {
      float v = out1[(size_t)row * F1 + i];
      rs[w][i] = v > 0.f ? v : __expf(v) - 1.f;
    }
    float acc = 0.f;
#pragma unroll 8
    for (int k = 0; k < F1; ++k) acc = fmaf(rs[w][k], W2[k * OUTD + lane], acc);
    h2[(size_t)row * OUTD + lane] = acc;
    float ps = acc * as2[lane], pd = acc * ad2[lane];
#pragma unroll
    for (int off = 32; off > 0; off >>= 1) {
      ps += __shfl_down(ps, off);
      pd += __shfl_down(pd, off);
    }
    if (lane == 0) { a_src2[row] = ps; a_dst2[row] = pd; }
  }
}

// fused softmax + aggregate, 4 dsts / 256-thread block, 64 threads per dst.
__global__ void k_agg2(const int* __restrict__ off, const int* __restrict__ csr,
                       const float* __restrict__ h2, const float* __restrict__ a_src2,
                       const float* __restrict__ a_dst2, const float* __restrict__ b2,
                       float* __restrict__ out, int N) {
  int q = threadIdx.x >> 6, c = threadIdx.x & 63;
  int d = blockIdx.x * 4 + q;
  if (d >= N) return;
  int beg = off[d], end = off[d + 1];
  float adl = a_dst2[d];
  float m = -1e30f;
  for (int j = beg; j < end; ++j) {
    int s = csr[j];
    float v = a_src2[s] + adl;
    v = v >= 0.f ? v : 0.2f * v;
    m = fmaxf(m, v);
  }
  float sum = 0.f, acc = 0.f;
  for (int j = beg; j < end; ++j) {
    int s = csr[j];
    float v = a_src2[s] + adl;
    v = v >= 0.f ? v : 0.2f * v;
    float p = __expf(v - m);
    sum += p;
    acc = fmaf(p, h2[(size_t)s * OUTD + c], acc);
  }
  out[(size_t)d * OUTD + c] = acc / (sum + 1e-16f) + b2[c];
}

extern "C" void kernel_launch(void* const* d_in, const int* in_sizes, int n_in,
                              void* d_out, int out_size, void* d_ws, size_t ws_size,
                              hipStream_t stream) {
  const float* x   = (const float*)d_in[0];
  const int*   ei  = (const int*)d_in[1];
  const float* W1  = (const float*)d_in[2];
  const float* as1 = (const float*)d_in[3];
  const float* ad1 = (const float*)d_in[4];
  const float* b1  = (const float*)d_in[5];
  const float* W2  = (const float*)d_in[6];
  const float* as2 = (const float*)d_in[7];
  const float* ad2 = (const float*)d_in[8];
  const float* b2  = (const float*)d_in[9];
  float* out = (float*)d_out;

  int N = in_sizes[0] / F1;
  int E = in_sizes[1] / 2;
  int ET = E + N;
  int NB = (N + SCANB - 1) / SCANB;   // scan blocks (must be <= 256; N=50000 -> 196)

  // workspace layout
  char* p = (char*)d_ws;
  int* deg    = (int*)p;            p += (size_t)N * 4;
  int* off    = (int*)p;            p += (size_t)(N + 1) * 4;
  int* cursor = (int*)p;            p += (size_t)N * 4;
  int* bsum   = (int*)p;            p += (size_t)SCANB * 4;
  int* csr    = (int*)p;            p += (size_t)ET * 4;
  float* h1     = (float*)p;        p += (size_t)N * F1 * 4;
  float* out1   = (float*)p;        p += (size_t)N * F1 * 4;
  float* a_src1 = (float*)p;        p += (size_t)N * HEADS * 4;
  float* a_dst1 = (float*)p;        p += (size_t)N * HEADS * 4;
  // layer-2 aliases (h1 region is dead after k_agg1 feeds gemm2's input out1)
  float* h2     = h1;               // N*OUTD
  float* a_src2 = a_src1;           // N
  float* a_dst2 = a_dst1;           // N

  // CSR build (shared by both layers)
  hipLaunchKernelGGL(k_zero,  dim3((N + 255) / 256), dim3(256), 0, stream, deg, N);
  hipLaunchKernelGGL(k_count, dim3((ET + 255) / 256), dim3(256), 0, stream, ei, E, N, deg);
  hipLaunchKernelGGL(k_scan1, dim3(NB), dim3(SCANB), 0, stream, deg, N, off, bsum);
  hipLaunchKernelGGL(k_scan2, dim3(1), dim3(SCANB), 0, stream, bsum, NB);
  hipLaunchKernelGGL(k_scan3, dim3(NB), dim3(SCANB), 0, stream, off, cursor, deg, bsum, N);
  hipLaunchKernelGGL(k_fill,  dim3((ET + 255) / 256), dim3(256), 0, stream, ei, E, N, cursor, csr);

  // layer 1
  hipLaunchKernelGGL(k_gemm1, dim3((N + 1) / 2), dim3(256), 0, stream,
                     x, W1, as1, ad1, h1, a_src1, a_dst1, N);
  hipLaunchKernelGGL(k_agg1, dim3((N + 1) / 2), dim3(256), 0, stream,
                     off, csr, h1, a_src1, a_dst1, b1, out1, N);

  // layer 2
  hipLaunchKernelGGL(k_gemm2, dim3((N + 3) / 4), dim3(256), 0, stream,
                     out1, W2, as2, ad2, h2, a_src2, a_dst2, N);
  hipLaunchKernelGGL(k_agg2, dim3((N + 3) / 4), dim3(256), 0, stream,
                     off, csr, h2, a_src2, a_dst2, b2, out, N);
}

// Round 3
// 467.019 us; speedup vs baseline: 3.0563x; 1.3538x over previous
//
#include <hip/hip_runtime.h>
#include <hip/hip_bf16.h>

#define HEADS 8
#define HID 16
#define F1 128    // HEADS*HID
#define OUTD 64
#define SCANB 256

typedef unsigned int uint;
typedef unsigned short ushort;

__device__ __forceinline__ ushort f2bf(float f) {
  __hip_bfloat16 b = __float2bfloat16(f);
  return *reinterpret_cast<ushort*>(&b);
}
__device__ __forceinline__ float bf2f_lo(uint w) {
  return __uint_as_float((w & 0xFFFFu) << 16);
}
__device__ __forceinline__ float bf2f_hi(uint w) {
  return __uint_as_float(w & 0xFFFF0000u);
}

// ---------------- CSR build ----------------

__global__ void k_zero(int* __restrict__ deg, int N) {
  int i = blockIdx.x * blockDim.x + threadIdx.x;
  if (i < N) deg[i] = 0;
}

__global__ void k_count(const int* __restrict__ ei, int E, int N, int* __restrict__ deg) {
  int e = blockIdx.x * blockDim.x + threadIdx.x;
  if (e >= E + N) return;
  int d = e < E ? ei[E + e] : e - E;
  atomicAdd(&deg[d], 1);
}

__global__ void k_scan1(const int* __restrict__ deg, int N, int* __restrict__ off,
                        int* __restrict__ bsum) {
  __shared__ int sm[SCANB];
  int t = threadIdx.x, i = blockIdx.x * SCANB + t;
  int v = i < N ? deg[i] : 0;
  sm[t] = v; __syncthreads();
  for (int o = 1; o < SCANB; o <<= 1) {
    int u = t >= o ? sm[t - o] : 0;
    __syncthreads();
    sm[t] += u;
    __syncthreads();
  }
  if (i < N) off[i + 1] = sm[t];
  if (t == SCANB - 1) bsum[blockIdx.x] = sm[t];
}

__global__ void k_scan2(int* __restrict__ bsum, int NB) {
  __shared__ int sm[SCANB];
  int t = threadIdx.x;
  int v = t < NB ? bsum[t] : 0;
  sm[t] = v; __syncthreads();
  for (int o = 1; o < SCANB; o <<= 1) {
    int u = t >= o ? sm[t - o] : 0;
    __syncthreads();
    sm[t] += u;
    __syncthreads();
  }
  if (t < NB) bsum[t] = sm[t] - v;   // exclusive
}

__global__ void k_scan3(int* __restrict__ off, int* __restrict__ cursor,
                        const int* __restrict__ deg, const int* __restrict__ bsum, int N) {
  int i = blockIdx.x * SCANB + threadIdx.x;
  if (i >= N) return;
  int v = off[i + 1] + bsum[blockIdx.x];
  off[i + 1] = v;
  cursor[i] = v - deg[i];
  if (i == 0) off[0] = 0;
}

__global__ void k_fill(const int* __restrict__ ei, int E, int N,
                       int* __restrict__ cursor, int* __restrict__ csr) {
  int e = blockIdx.x * blockDim.x + threadIdx.x;
  if (e >= E + N) return;
  int s = e < E ? ei[e] : e - E;
  int d = e < E ? ei[E + e] : e - E;
  int pos = atomicAdd(&cursor[d], 1);
  csr[pos] = s;
}

// ---------------- layer 1 ----------------

// h1 = x @ W1, stored packed bf16 (2 ch / uint); + per-head attention dots (f32)
__global__ void k_gemm1(const float* __restrict__ x, const float* __restrict__ W1,
                        const float* __restrict__ as, const float* __restrict__ ad,
                        uint* __restrict__ h1b, float* __restrict__ a_src,
                        float* __restrict__ a_dst, int N) {
  __shared__ float xs[2][F1];
  __shared__ float hs[2][F1];
  int l = threadIdx.x >> 7, c = threadIdx.x & 127;
  int row = blockIdx.x * 2 + l;
  bool act = row < N;
  xs[l][c] = act ? x[(size_t)row * F1 + c] : 0.f;
  __syncthreads();
  float acc = 0.f;
#pragma unroll 8
  for (int k = 0; k < F1; ++k) acc = fmaf(xs[l][k], W1[k * F1 + c], acc);
  hs[l][c] = acc;
  __syncthreads();
  if (act && c < 64) {
    uint w = (uint)f2bf(hs[l][2 * c]) | ((uint)f2bf(hs[l][2 * c + 1]) << 16);
    h1b[(size_t)row * 64 + c] = w;
  }
  if (act && c >= 64 && c < 64 + HEADS) {
    int h = c - 64;
    float ss = 0.f, sd = 0.f;
#pragma unroll
    for (int j = 0; j < HID; ++j) {
      float v = hs[l][h * HID + j];
      ss = fmaf(v, as[h * HID + j], ss);
      sd = fmaf(v, ad[h * HID + j], sd);
    }
    a_src[row * HEADS + h] = ss;
    a_dst[row * HEADS + h] = sd;
  }
}

// per-(dst,head) online softmax stats over in-edges: m, 1/sum. 8 lanes/dst.
__global__ void k_stats1(const int* __restrict__ off, const int* __restrict__ csr,
                         const float* __restrict__ a_src, const float* __restrict__ a_dst,
                         float* __restrict__ m1v, float* __restrict__ s1v, int N) {
  int g = threadIdx.x >> 3, h = threadIdx.x & 7;
  int d = blockIdx.x * 32 + g;
  if (d >= N) return;
  int beg = off[d], end = off[d + 1];
  float adl = a_dst[d * HEADS + h];
  float m = -1e30f, sum = 0.f;
  for (int j = beg; j < end; ++j) {
    int s = csr[j];
    float v = a_src[s * HEADS + h] + adl;
    v = v >= 0.f ? v : 0.2f * v;
    float mn = fmaxf(m, v);
    sum = sum * __expf(m - mn) + __expf(v - mn);
    m = mn;
  }
  m1v[d * HEADS + h] = m;
  s1v[d * HEADS + h] = 1.f / (sum + 1e-16f);
}

// single-pass aggregate: 1 wave per dst, thread c owns channels {2c,2c+1}, head c>>3
__global__ void k_agg1(const int* __restrict__ off, const int* __restrict__ csr,
                       const uint* __restrict__ h1b, const float* __restrict__ a_src,
                       const float* __restrict__ a_dst, const float* __restrict__ m1v,
                       const float* __restrict__ s1v, const float* __restrict__ b1,
                       float* __restrict__ out1, int N) {
  int w = threadIdx.x >> 6, c = threadIdx.x & 63, h = c >> 3;
  int d = blockIdx.x * 4 + w;
  if (d >= N) return;
  int beg = off[d], end = off[d + 1];
  float adl = a_dst[d * HEADS + h];
  float m = m1v[d * HEADS + h];
  float inv = s1v[d * HEADS + h];
  float acc0 = 0.f, acc1 = 0.f;
  for (int j = beg; j < end; ++j) {
    int s = csr[j];
    float v = a_src[s * HEADS + h] + adl;
    v = v >= 0.f ? v : 0.2f * v;
    float p = __expf(v - m) * inv;
    uint wd = h1b[(size_t)s * 64 + c];
    acc0 = fmaf(p, bf2f_lo(wd), acc0);
    acc1 = fmaf(p, bf2f_hi(wd), acc1);
  }
  float2 o;
  o.x = acc0 + b1[2 * c];
  o.y = acc1 + b1[2 * c + 1];
  *reinterpret_cast<float2*>(&out1[(size_t)d * F1 + 2 * c]) = o;
}

// ---------------- layer 2 ----------------

// h2 = elu(out1) @ W2, packed bf16; scalar attention dots via wave reduce. 1 row/wave.
__global__ void k_gemm2(const float* __restrict__ out1, const float* __restrict__ W2,
                        const float* __restrict__ as2, const float* __restrict__ ad2,
                        uint* __restrict__ h2b, float* __restrict__ a_src2,
                        float* __restrict__ a_dst2, int N) {
  __shared__ float rs[4][F1];
  int w = threadIdx.x >> 6, lane = threadIdx.x & 63;
  int row = blockIdx.x * 4 + w;
  bool act = row < N;
  if (act) {
#pragma unroll
    for (int i = lane; i < F1; i += 64) {
      float v = out1[(size_t)row * F1 + i];
      rs[w][i] = v > 0.f ? v : __expf(v) - 1.f;
    }
    float acc = 0.f;
#pragma unroll 8
    for (int k = 0; k < F1; ++k) acc = fmaf(rs[w][k], W2[k * OUTD + lane], acc);
    // pack 2 channels/uint: lane<32 packs lanes 2l, 2l+1
    float a0 = __shfl(acc, 2 * (lane & 31));
    float a1 = __shfl(acc, 2 * (lane & 31) + 1);
    if (lane < 32)
      h2b[(size_t)row * 32 + lane] = (uint)f2bf(a0) | ((uint)f2bf(a1) << 16);
    float ps = acc * as2[lane], pd = acc * ad2[lane];
#pragma unroll
    for (int off = 32; off > 0; off >>= 1) {
      ps += __shfl_down(ps, off);
      pd += __shfl_down(pd, off);
    }
    if (lane == 0) { a_src2[row] = ps; a_dst2[row] = pd; }
  }
}

// per-dst online softmax stats (H=1). 1 thread/dst.
__global__ void k_stats2(const int* __restrict__ off, const int* __restrict__ csr,
                         const float* __restrict__ a_src2, const float* __restrict__ a_dst2,
                         float* __restrict__ m2v, float* __restrict__ s2v, int N) {
  int d = blockIdx.x * blockDim.x + threadIdx.x;
  if (d >= N) return;
  int beg = off[d], end = off[d + 1];
  float adl = a_dst2[d];
  float m = -1e30f, sum = 0.f;
  for (int j = beg; j < end; ++j) {
    int s = csr[j];
    float v = a_src2[s] + adl;
    v = v >= 0.f ? v : 0.2f * v;
    float mn = fmaxf(m, v);
    sum = sum * __expf(m - mn) + __expf(v - mn);
    m = mn;
  }
  m2v[d] = m;
  s2v[d] = 1.f / (sum + 1e-16f);
}

// single-pass aggregate: 1 wave per dst, thread c owns channel c (ushort load)
__global__ void k_agg2(const int* __restrict__ off, const int* __restrict__ csr,
                       const ushort* __restrict__ h2u, const float* __restrict__ a_src2,
                       const float* __restrict__ a_dst2, const float* __restrict__ m2v,
                       const float* __restrict__ s2v, const float* __restrict__ b2,
                       float* __restrict__ out, int N) {
  int w = threadIdx.x >> 6, c = threadIdx.x & 63;
  int d = blockIdx.x * 4 + w;
  if (d >= N) return;
  int beg = off[d], end = off[d + 1];
  float adl = a_dst2[d];
  float m = m2v[d];
  float inv = s2v[d];
  float acc = 0.f;
  for (int j = beg; j < end; ++j) {
    int s = csr[j];
    float v = a_src2[s] + adl;
    v = v >= 0.f ? v : 0.2f * v;
    float p = __expf(v - m) * inv;
    float f = __uint_as_float((uint)h2u[(size_t)s * OUTD + c] << 16);
    acc = fmaf(p, f, acc);
  }
  out[(size_t)d * OUTD + c] = acc + b2[c];
}

extern "C" void kernel_launch(void* const* d_in, const int* in_sizes, int n_in,
                              void* d_out, int out_size, void* d_ws, size_t ws_size,
                              hipStream_t stream) {
  const float* x   = (const float*)d_in[0];
  const int*   ei  = (const int*)d_in[1];
  const float* W1  = (const float*)d_in[2];
  const float* as1 = (const float*)d_in[3];
  const float* ad1 = (const float*)d_in[4];
  const float* b1  = (const float*)d_in[5];
  const float* W2  = (const float*)d_in[6];
  const float* as2 = (const float*)d_in[7];
  const float* ad2 = (const float*)d_in[8];
  const float* b2  = (const float*)d_in[9];
  float* out = (float*)d_out;

  int N = in_sizes[0] / F1;
  int E = in_sizes[1] / 2;
  int ET = E + N;
  int NB = (N + SCANB - 1) / SCANB;

  // workspace layout
  char* p = (char*)d_ws;
  int* deg    = (int*)p;            p += (size_t)N * 4;
  int* off    = (int*)p;            p += (size_t)(N + 1) * 4;
  int* cursor = (int*)p;            p += (size_t)N * 4;
  int* bsum   = (int*)p;            p += (size_t)SCANB * 4;
  int* csr    = (int*)p;            p += (size_t)ET * 4;
  uint* h1b     = (uint*)p;         p += (size_t)N * 64 * 4;
  float* out1   = (float*)p;        p += (size_t)N * F1 * 4;
  float* a_src1 = (float*)p;        p += (size_t)N * HEADS * 4;
  float* a_dst1 = (float*)p;        p += (size_t)N * HEADS * 4;
  float* m1v    = (float*)p;        p += (size_t)N * HEADS * 4;
  float* s1v    = (float*)p;        p += (size_t)N * HEADS * 4;
  // layer-2 aliases over dead layer-1 regions
  uint* h2b     = h1b;              // N*32 uint (h1b dead after k_agg1)
  float* a_src2 = a_src1;           // N
  float* a_dst2 = a_dst1;           // N
  float* m2v    = m1v;              // N
  float* s2v    = s1v;              // N

  // CSR build (shared by both layers)
  hipLaunchKernelGGL(k_zero,  dim3((N + 255) / 256), dim3(256), 0, stream, deg, N);
  hipLaunchKernelGGL(k_count, dim3((ET + 255) / 256), dim3(256), 0, stream, ei, E, N, deg);
  hipLaunchKernelGGL(k_scan1, dim3(NB), dim3(SCANB), 0, stream, deg, N, off, bsum);
  hipLaunchKernelGGL(k_scan2, dim3(1), dim3(SCANB), 0, stream, bsum, NB);
  hipLaunchKernelGGL(k_scan3, dim3(NB), dim3(SCANB), 0, stream, off, cursor, deg, bsum, N);
  hipLaunchKernelGGL(k_fill,  dim3((ET + 255) / 256), dim3(256), 0, stream, ei, E, N, cursor, csr);

  // layer 1
  hipLaunchKernelGGL(k_gemm1, dim3((N + 1) / 2), dim3(256), 0, stream,
                     x, W1, as1, ad1, h1b, a_src1, a_dst1, N);
  hipLaunchKernelGGL(k_stats1, dim3((N + 31) / 32), dim3(256), 0, stream,
                     off, csr, a_src1, a_dst1, m1v, s1v, N);
  hipLaunchKernelGGL(k_agg1, dim3((N + 3) / 4), dim3(256), 0, stream,
                     off, csr, h1b, a_src1, a_dst1, m1v, s1v, b1, out1, N);

  // layer 2
  hipLaunchKernelGGL(k_gemm2, dim3((N + 3) / 4), dim3(256), 0, stream,
                     out1, W2, as2, ad2, h2b, a_src2, a_dst2, N);
  hipLaunchKernelGGL(k_stats2, dim3((N + 255) / 256), dim3(256), 0, stream,
                     off, csr, a_src2, a_dst2, m2v, s2v, N);
  hipLaunchKernelGGL(k_agg2, dim3((N + 3) / 4), dim3(256), 0, stream,
                     off, csr, (const ushort*)h2b, a_src2, a_dst2, m2v, s2v, b2, out, N);
}

// Round 4
// 376.586 us; speedup vs baseline: 3.7902x; 1.2401x over previous
//
#include <hip/hip_runtime.h>
#include <hip/hip_bf16.h>

#define HEADS 8
#define HID 16
#define F1 128    // HEADS*HID
#define OUTD 64
#define SCANB 256
#define XS_STRIDE 68   // padded LDS stride: 16B-aligned rows (68*4=272=17*16)

typedef unsigned int uint;
typedef unsigned short ushort;

__device__ __forceinline__ ushort f2bf(float f) {
  __hip_bfloat16 b = __float2bfloat16(f);
  return *reinterpret_cast<ushort*>(&b);
}
__device__ __forceinline__ float bf2f_lo(uint w) {
  return __uint_as_float((w & 0xFFFFu) << 16);
}
__device__ __forceinline__ float bf2f_hi(uint w) {
  return __uint_as_float(w & 0xFFFF0000u);
}

// ---------------- CSR build ----------------

__global__ void k_zero(int* __restrict__ deg, int N) {
  int i = blockIdx.x * blockDim.x + threadIdx.x;
  if (i < N) deg[i] = 0;
}

__global__ void k_count(const int* __restrict__ ei, int E, int N, int* __restrict__ deg) {
  int e = blockIdx.x * blockDim.x + threadIdx.x;
  if (e >= E + N) return;
  int d = e < E ? ei[E + e] : e - E;
  atomicAdd(&deg[d], 1);
}

__global__ void k_scan1(const int* __restrict__ deg, int N, int* __restrict__ off,
                        int* __restrict__ bsum) {
  __shared__ int sm[SCANB];
  int t = threadIdx.x, i = blockIdx.x * SCANB + t;
  int v = i < N ? deg[i] : 0;
  sm[t] = v; __syncthreads();
  for (int o = 1; o < SCANB; o <<= 1) {
    int u = t >= o ? sm[t - o] : 0;
    __syncthreads();
    sm[t] += u;
    __syncthreads();
  }
  if (i < N) off[i + 1] = sm[t];
  if (t == SCANB - 1) bsum[blockIdx.x] = sm[t];
}

__global__ void k_scan2(int* __restrict__ bsum, int NB) {
  __shared__ int sm[SCANB];
  int t = threadIdx.x;
  int v = t < NB ? bsum[t] : 0;
  sm[t] = v; __syncthreads();
  for (int o = 1; o < SCANB; o <<= 1) {
    int u = t >= o ? sm[t - o] : 0;
    __syncthreads();
    sm[t] += u;
    __syncthreads();
  }
  if (t < NB) bsum[t] = sm[t] - v;   // exclusive
}

__global__ void k_scan3(int* __restrict__ off, int* __restrict__ cursor,
                        const int* __restrict__ deg, const int* __restrict__ bsum, int N) {
  int i = blockIdx.x * SCANB + threadIdx.x;
  if (i >= N) return;
  int v = off[i + 1] + bsum[blockIdx.x];
  off[i + 1] = v;
  cursor[i] = v - deg[i];
  if (i == 0) off[0] = 0;
}

__global__ void k_fill(const int* __restrict__ ei, int E, int N,
                       int* __restrict__ cursor, int* __restrict__ csr) {
  int e = blockIdx.x * blockDim.x + threadIdx.x;
  if (e >= E + N) return;
  int s = e < E ? ei[e] : e - E;
  int d = e < E ? ei[E + e] : e - E;
  int pos = atomicAdd(&cursor[d], 1);
  csr[pos] = s;
}

// ---------------- layer 1 GEMM ----------------
// 64 rows x 128 cols per block; 256 threads; thread owns 8 rows x 4 cols.
// x tile staged transposed in LDS; W1 from L2 with 8x in-block reuse.
__global__ __launch_bounds__(256) void k_gemm1(
    const float* __restrict__ x, const float* __restrict__ W1,
    const float* __restrict__ as, const float* __restrict__ ad,
    uint* __restrict__ h1b, float* __restrict__ a_src,
    float* __restrict__ a_dst, int N) {
  __shared__ float xs[F1 * XS_STRIDE];   // xs[k][row], 34 KB
  int tx = threadIdx.x;
  int cg = tx & 31;          // col group: cols 4cg..4cg+3
  int rg = tx >> 5;          // row group: rows 8rg..8rg+7
  int r0 = blockIdx.x * 64;

  // stage x[r0..r0+63][0..127] -> xs[k][row]; lanes vary row -> conflict-free writes
  {
    int row = tx & 63, kq0 = tx >> 6;   // kq0 in [0,4)
#pragma unroll
    for (int it = 0; it < 8; ++it) {
      int k4 = (it * 4 + kq0) * 4;
      float4 v = make_float4(0.f, 0.f, 0.f, 0.f);
      if (r0 + row < N) v = *reinterpret_cast<const float4*>(&x[(size_t)(r0 + row) * F1 + k4]);
      xs[(k4 + 0) * XS_STRIDE + row] = v.x;
      xs[(k4 + 1) * XS_STRIDE + row] = v.y;
      xs[(k4 + 2) * XS_STRIDE + row] = v.z;
      xs[(k4 + 3) * XS_STRIDE + row] = v.w;
    }
  }
  __syncthreads();

  float acc[8][4];
#pragma unroll
  for (int i = 0; i < 8; ++i)
#pragma unroll
    for (int j = 0; j < 4; ++j) acc[i][j] = 0.f;

#pragma unroll 4
  for (int k = 0; k < F1; ++k) {
    float4 w = *reinterpret_cast<const float4*>(&W1[k * F1 + 4 * cg]);
    float4 xa = *reinterpret_cast<const float4*>(&xs[k * XS_STRIDE + rg * 8]);
    float4 xb = *reinterpret_cast<const float4*>(&xs[k * XS_STRIDE + rg * 8 + 4]);
    const float xr[8] = {xa.x, xa.y, xa.z, xa.w, xb.x, xb.y, xb.z, xb.w};
#pragma unroll
    for (int i = 0; i < 8; ++i) {
      acc[i][0] = fmaf(xr[i], w.x, acc[i][0]);
      acc[i][1] = fmaf(xr[i], w.y, acc[i][1]);
      acc[i][2] = fmaf(xr[i], w.z, acc[i][2]);
      acc[i][3] = fmaf(xr[i], w.w, acc[i][3]);
    }
  }

  // epilogue: packed bf16 store + attention dots (4-lane shfl reduce)
  float4 as4 = *reinterpret_cast<const float4*>(&as[4 * cg]);
  float4 ad4 = *reinterpret_cast<const float4*>(&ad[4 * cg]);
  int h = cg >> 2;
#pragma unroll
  for (int i = 0; i < 8; ++i) {
    int row = r0 + rg * 8 + i;
    bool act = row < N;
    if (act) {
      uint2 pk;
      pk.x = (uint)f2bf(acc[i][0]) | ((uint)f2bf(acc[i][1]) << 16);
      pk.y = (uint)f2bf(acc[i][2]) | ((uint)f2bf(acc[i][3]) << 16);
      *reinterpret_cast<uint2*>(&h1b[(size_t)row * 64 + 2 * cg]) = pk;
    }
    float ps = acc[i][0] * as4.x + acc[i][1] * as4.y + acc[i][2] * as4.z + acc[i][3] * as4.w;
    float pd = acc[i][0] * ad4.x + acc[i][1] * ad4.y + acc[i][2] * ad4.z + acc[i][3] * ad4.w;
    ps += __shfl_xor(ps, 1); ps += __shfl_xor(ps, 2);
    pd += __shfl_xor(pd, 1); pd += __shfl_xor(pd, 2);
    if (act && (cg & 3) == 0) {
      a_src[row * HEADS + h] = ps;
      a_dst[row * HEADS + h] = pd;
    }
  }
}

// per-(dst,head) online softmax stats over in-edges: m, 1/sum. 8 lanes/dst.
__global__ void k_stats1(const int* __restrict__ off, const int* __restrict__ csr,
                         const float* __restrict__ a_src, const float* __restrict__ a_dst,
                         float* __restrict__ m1v, float* __restrict__ s1v, int N) {
  int g = threadIdx.x >> 3, h = threadIdx.x & 7;
  int d = blockIdx.x * 32 + g;
  if (d >= N) return;
  int beg = off[d], end = off[d + 1];
  float adl = a_dst[d * HEADS + h];
  float m = -1e30f, sum = 0.f;
  for (int j = beg; j < end; ++j) {
    int s = csr[j];
    float v = a_src[s * HEADS + h] + adl;
    v = v >= 0.f ? v : 0.2f * v;
    float mn = fmaxf(m, v);
    sum = sum * __expf(m - mn) + __expf(v - mn);
    m = mn;
  }
  m1v[d * HEADS + h] = m;
  s1v[d * HEADS + h] = 1.f / (sum + 1e-16f);
}

// single-pass aggregate: 1 wave per dst, thread c owns channels {2c,2c+1}, head c>>3
__global__ void k_agg1(const int* __restrict__ off, const int* __restrict__ csr,
                       const uint* __restrict__ h1b, const float* __restrict__ a_src,
                       const float* __restrict__ a_dst, const float* __restrict__ m1v,
                       const float* __restrict__ s1v, const float* __restrict__ b1,
                       float* __restrict__ out1, int N) {
  int w = threadIdx.x >> 6, c = threadIdx.x & 63, h = c >> 3;
  int d = blockIdx.x * 4 + w;
  if (d >= N) return;
  int beg = off[d], end = off[d + 1];
  float adl = a_dst[d * HEADS + h];
  float m = m1v[d * HEADS + h];
  float inv = s1v[d * HEADS + h];
  float acc0 = 0.f, acc1 = 0.f;
  for (int j = beg; j < end; ++j) {
    int s = csr[j];
    float v = a_src[s * HEADS + h] + adl;
    v = v >= 0.f ? v : 0.2f * v;
    float p = __expf(v - m) * inv;
    uint wd = h1b[(size_t)s * 64 + c];
    acc0 = fmaf(p, bf2f_lo(wd), acc0);
    acc1 = fmaf(p, bf2f_hi(wd), acc1);
  }
  float2 o;
  o.x = acc0 + b1[2 * c];
  o.y = acc1 + b1[2 * c + 1];
  *reinterpret_cast<float2*>(&out1[(size_t)d * F1 + 2 * c]) = o;
}

// ---------------- layer 2 GEMM ----------------
// 64 rows x 64 cols per block; 256 threads; thread owns 4 rows x 4 cols.
// ELU fused into staging; scalar attention dots via 16-lane shfl reduce.
__global__ __launch_bounds__(256) void k_gemm2(
    const float* __restrict__ out1, const float* __restrict__ W2,
    const float* __restrict__ as2, const float* __restrict__ ad2,
    uint* __restrict__ h2b, float* __restrict__ a_src2,
    float* __restrict__ a_dst2, int N) {
  __shared__ float xs[F1 * XS_STRIDE];   // xs[k][row]
  int tx = threadIdx.x;
  int cg = tx & 15;          // cols 4cg..4cg+3
  int rg = tx >> 4;          // rows 4rg..4rg+3 (rg in [0,16))
  int r0 = blockIdx.x * 64;

  {
    int row = tx & 63, kq0 = tx >> 6;
#pragma unroll
    for (int it = 0; it < 8; ++it) {
      int k4 = (it * 4 + kq0) * 4;
      float4 v = make_float4(0.f, 0.f, 0.f, 0.f);
      if (r0 + row < N) v = *reinterpret_cast<const float4*>(&out1[(size_t)(r0 + row) * F1 + k4]);
      v.x = v.x > 0.f ? v.x : __expf(v.x) - 1.f;
      v.y = v.y > 0.f ? v.y : __expf(v.y) - 1.f;
      v.z = v.z > 0.f ? v.z : __expf(v.z) - 1.f;
      v.w = v.w > 0.f ? v.w : __expf(v.w) - 1.f;
      xs[(k4 + 0) * XS_STRIDE + row] = v.x;
      xs[(k4 + 1) * XS_STRIDE + row] = v.y;
      xs[(k4 + 2) * XS_STRIDE + row] = v.z;
      xs[(k4 + 3) * XS_STRIDE + row] = v.w;
    }
  }
  __syncthreads();

  float acc[4][4];
#pragma unroll
  for (int i = 0; i < 4; ++i)
#pragma unroll
    for (int j = 0; j < 4; ++j) acc[i][j] = 0.f;

#pragma unroll 4
  for (int k = 0; k < F1; ++k) {
    float4 w = *reinterpret_cast<const float4*>(&W2[k * OUTD + 4 * cg]);
    float4 xa = *reinterpret_cast<const float4*>(&xs[k * XS_STRIDE + rg * 4]);
    const float xr[4] = {xa.x, xa.y, xa.z, xa.w};
#pragma unroll
    for (int i = 0; i < 4; ++i) {
      acc[i][0] = fmaf(xr[i], w.x, acc[i][0]);
      acc[i][1] = fmaf(xr[i], w.y, acc[i][1]);
      acc[i][2] = fmaf(xr[i], w.z, acc[i][2]);
      acc[i][3] = fmaf(xr[i], w.w, acc[i][3]);
    }
  }

  float4 as4 = *reinterpret_cast<const float4*>(&as2[4 * cg]);
  float4 ad4 = *reinterpret_cast<const float4*>(&ad2[4 * cg]);
#pragma unroll
  for (int i = 0; i < 4; ++i) {
    int row = r0 + rg * 4 + i;
    bool act = row < N;
    if (act) {
      uint2 pk;
      pk.x = (uint)f2bf(acc[i][0]) | ((uint)f2bf(acc[i][1]) << 16);
      pk.y = (uint)f2bf(acc[i][2]) | ((uint)f2bf(acc[i][3]) << 16);
      *reinterpret_cast<uint2*>(&h2b[(size_t)row * 32 + 2 * cg]) = pk;
    }
    float ps = acc[i][0] * as4.x + acc[i][1] * as4.y + acc[i][2] * as4.z + acc[i][3] * as4.w;
    float pd = acc[i][0] * ad4.x + acc[i][1] * ad4.y + acc[i][2] * ad4.z + acc[i][3] * ad4.w;
    ps += __shfl_xor(ps, 1); ps += __shfl_xor(ps, 2);
    ps += __shfl_xor(ps, 4); ps += __shfl_xor(ps, 8);
    pd += __shfl_xor(pd, 1); pd += __shfl_xor(pd, 2);
    pd += __shfl_xor(pd, 4); pd += __shfl_xor(pd, 8);
    if (act && cg == 0) {
      a_src2[row] = ps;
      a_dst2[row] = pd;
    }
  }
}

// per-dst online softmax stats (H=1). 1 thread/dst.
__global__ void k_stats2(const int* __restrict__ off, const int* __restrict__ csr,
                         const float* __restrict__ a_src2, const float* __restrict__ a_dst2,
                         float* __restrict__ m2v, float* __restrict__ s2v, int N) {
  int d = blockIdx.x * blockDim.x + threadIdx.x;
  if (d >= N) return;
  int beg = off[d], end = off[d + 1];
  float adl = a_dst2[d];
  float m = -1e30f, sum = 0.f;
  for (int j = beg; j < end; ++j) {
    int s = csr[j];
    float v = a_src2[s] + adl;
    v = v >= 0.f ? v : 0.2f * v;
    float mn = fmaxf(m, v);
    sum = sum * __expf(m - mn) + __expf(v - mn);
    m = mn;
  }
  m2v[d] = m;
  s2v[d] = 1.f / (sum + 1e-16f);
}

// single-pass aggregate: 1 wave per dst, thread c owns channel c (ushort load)
__global__ void k_agg2(const int* __restrict__ off, const int* __restrict__ csr,
                       const ushort* __restrict__ h2u, const float* __restrict__ a_src2,
                       const float* __restrict__ a_dst2, const float* __restrict__ m2v,
                       const float* __restrict__ s2v, const float* __restrict__ b2,
                       float* __restrict__ out, int N) {
  int w = threadIdx.x >> 6, c = threadIdx.x & 63;
  int d = blockIdx.x * 4 + w;
  if (d >= N) return;
  int beg = off[d], end = off[d + 1];
  float adl = a_dst2[d];
  float m = m2v[d];
  float inv = s2v[d];
  float acc = 0.f;
  for (int j = beg; j < end; ++j) {
    int s = csr[j];
    float v = a_src2[s] + adl;
    v = v >= 0.f ? v : 0.2f * v;
    float p = __expf(v - m) * inv;
    float f = __uint_as_float((uint)h2u[(size_t)s * OUTD + c] << 16);
    acc = fmaf(p, f, acc);
  }
  out[(size_t)d * OUTD + c] = acc + b2[c];
}

extern "C" void kernel_launch(void* const* d_in, const int* in_sizes, int n_in,
                              void* d_out, int out_size, void* d_ws, size_t ws_size,
                              hipStream_t stream) {
  const float* x   = (const float*)d_in[0];
  const int*   ei  = (const int*)d_in[1];
  const float* W1  = (const float*)d_in[2];
  const float* as1 = (const float*)d_in[3];
  const float* ad1 = (const float*)d_in[4];
  const float* b1  = (const float*)d_in[5];
  const float* W2  = (const float*)d_in[6];
  const float* as2 = (const float*)d_in[7];
  const float* ad2 = (const float*)d_in[8];
  const float* b2  = (const float*)d_in[9];
  float* out = (float*)d_out;

  int N = in_sizes[0] / F1;
  int E = in_sizes[1] / 2;
  int ET = E + N;
  int NB = (N + SCANB - 1) / SCANB;
  int NT = (N + 63) / 64;   // GEMM tiles

  // workspace layout
  char* p = (char*)d_ws;
  int* deg    = (int*)p;            p += (size_t)N * 4;
  int* off    = (int*)p;            p += (size_t)(N + 1) * 4;
  int* cursor = (int*)p;            p += (size_t)N * 4;
  int* bsum   = (int*)p;            p += (size_t)SCANB * 4;
  int* csr    = (int*)p;            p += (size_t)ET * 4;
  uint* h1b     = (uint*)p;         p += (size_t)N * 64 * 4;
  float* out1   = (float*)p;        p += (size_t)N * F1 * 4;
  float* a_src1 = (float*)p;        p += (size_t)N * HEADS * 4;
  float* a_dst1 = (float*)p;        p += (size_t)N * HEADS * 4;
  float* m1v    = (float*)p;        p += (size_t)N * HEADS * 4;
  float* s1v    = (float*)p;        p += (size_t)N * HEADS * 4;
  // layer-2 aliases over dead layer-1 regions
  uint* h2b     = h1b;              // N*32 uint (h1b dead after k_agg1)
  float* a_src2 = a_src1;           // N
  float* a_dst2 = a_dst1;           // N
  float* m2v    = m1v;              // N
  float* s2v    = s1v;              // N

  // CSR build (shared by both layers)
  hipLaunchKernelGGL(k_zero,  dim3((N + 255) / 256), dim3(256), 0, stream, deg, N);
  hipLaunchKernelGGL(k_count, dim3((ET + 255) / 256), dim3(256), 0, stream, ei, E, N, deg);
  hipLaunchKernelGGL(k_scan1, dim3(NB), dim3(SCANB), 0, stream, deg, N, off, bsum);
  hipLaunchKernelGGL(k_scan2, dim3(1), dim3(SCANB), 0, stream, bsum, NB);
  hipLaunchKernelGGL(k_scan3, dim3(NB), dim3(SCANB), 0, stream, off, cursor, deg, bsum, N);
  hipLaunchKernelGGL(k_fill,  dim3((ET + 255) / 256), dim3(256), 0, stream, ei, E, N, cursor, csr);

  // layer 1
  hipLaunchKernelGGL(k_gemm1, dim3(NT), dim3(256), 0, stream,
                     x, W1, as1, ad1, h1b, a_src1, a_dst1, N);
  hipLaunchKernelGGL(k_stats1, dim3((N + 31) / 32), dim3(256), 0, stream,
                     off, csr, a_src1, a_dst1, m1v, s1v, N);
  hipLaunchKernelGGL(k_agg1, dim3((N + 3) / 4), dim3(256), 0, stream,
                     off, csr, h1b, a_src1, a_dst1, m1v, s1v, b1, out1, N);

  // layer 2
  hipLaunchKernelGGL(k_gemm2, dim3(NT), dim3(256), 0, stream,
                     out1, W2, as2, ad2, h2b, a_src2, a_dst2, N);
  hipLaunchKernelGGL(k_stats2, dim3((N + 255) / 256), dim3(256), 0, stream,
                     off, csr, a_src2, a_dst2, m2v, s2v, N);
  hipLaunchKernelGGL(k_agg2, dim3((N + 3) / 4), dim3(256), 0, stream,
                     off, csr, (const ushort*)h2b, a_src2, a_dst2, m2v, s2v, b2, out, N);
}

// Round 5
// 254.654 us; speedup vs baseline: 5.6051x; 1.4788x over previous
//
#include <hip/hip_runtime.h>
#include <hip/hip_bf16.h>

#define HEADS 8
#define HID 16
#define F1 128    // HEADS*HID
#define OUTD 64
#define SCANB 256
#define XS_STRIDE 68   // padded LDS stride: 16B-aligned rows (68*4=272=17*16)

typedef unsigned int uint;
typedef unsigned short ushort;

__device__ __forceinline__ ushort f2bf(float f) {
  __hip_bfloat16 b = __float2bfloat16(f);
  return *reinterpret_cast<ushort*>(&b);
}
__device__ __forceinline__ float bf2f_lo(uint w) {
  return __uint_as_float((w & 0xFFFFu) << 16);
}
__device__ __forceinline__ float bf2f_hi(uint w) {
  return __uint_as_float(w & 0xFFFF0000u);
}

// ---------------- CSR build ----------------

__global__ void k_zero(int* __restrict__ deg, int N) {
  int i = blockIdx.x * blockDim.x + threadIdx.x;
  if (i < N) deg[i] = 0;
}

__global__ void k_count(const int* __restrict__ ei, int E, int N, int* __restrict__ deg) {
  int e = blockIdx.x * blockDim.x + threadIdx.x;
  if (e >= E + N) return;
  int d = e < E ? ei[E + e] : e - E;
  atomicAdd(&deg[d], 1);
}

__global__ void k_scan1(const int* __restrict__ deg, int N, int* __restrict__ off,
                        int* __restrict__ bsum) {
  __shared__ int sm[SCANB];
  int t = threadIdx.x, i = blockIdx.x * SCANB + t;
  int v = i < N ? deg[i] : 0;
  sm[t] = v; __syncthreads();
  for (int o = 1; o < SCANB; o <<= 1) {
    int u = t >= o ? sm[t - o] : 0;
    __syncthreads();
    sm[t] += u;
    __syncthreads();
  }
  if (i < N) off[i + 1] = sm[t];
  if (t == SCANB - 1) bsum[blockIdx.x] = sm[t];
}

__global__ void k_scan2(int* __restrict__ bsum, int NB) {
  __shared__ int sm[SCANB];
  int t = threadIdx.x;
  int v = t < NB ? bsum[t] : 0;
  sm[t] = v; __syncthreads();
  for (int o = 1; o < SCANB; o <<= 1) {
    int u = t >= o ? sm[t - o] : 0;
    __syncthreads();
    sm[t] += u;
    __syncthreads();
  }
  if (t < NB) bsum[t] = sm[t] - v;   // exclusive
}

__global__ void k_scan3(int* __restrict__ off, int* __restrict__ cursor,
                        const int* __restrict__ deg, const int* __restrict__ bsum, int N) {
  int i = blockIdx.x * SCANB + threadIdx.x;
  if (i >= N) return;
  int v = off[i + 1] + bsum[blockIdx.x];
  off[i + 1] = v;
  cursor[i] = v - deg[i];
  if (i == 0) off[0] = 0;
}

__global__ void k_fill(const int* __restrict__ ei, int E, int N,
                       int* __restrict__ cursor, int* __restrict__ csr) {
  int e = blockIdx.x * blockDim.x + threadIdx.x;
  if (e >= E + N) return;
  int s = e < E ? ei[e] : e - E;
  int d = e < E ? ei[E + e] : e - E;
  int pos = atomicAdd(&cursor[d], 1);
  csr[pos] = s;
}

// ---------------- layer 1 GEMM ----------------
// 64 rows x 128 cols per block; 256 threads; thread owns 8 rows x 4 cols.
__global__ __launch_bounds__(256) void k_gemm1(
    const float* __restrict__ x, const float* __restrict__ W1,
    const float* __restrict__ as, const float* __restrict__ ad,
    uint* __restrict__ h1b, float* __restrict__ a_src,
    float* __restrict__ a_dst, int N) {
  __shared__ float xs[F1 * XS_STRIDE];   // xs[k][row], 34 KB
  int tx = threadIdx.x;
  int cg = tx & 31;          // col group: cols 4cg..4cg+3
  int rg = tx >> 5;          // row group: rows 8rg..8rg+7
  int r0 = blockIdx.x * 64;

  {
    int row = tx & 63, kq0 = tx >> 6;   // kq0 in [0,4)
#pragma unroll
    for (int it = 0; it < 8; ++it) {
      int k4 = (it * 4 + kq0) * 4;
      float4 v = make_float4(0.f, 0.f, 0.f, 0.f);
      if (r0 + row < N) v = *reinterpret_cast<const float4*>(&x[(size_t)(r0 + row) * F1 + k4]);
      xs[(k4 + 0) * XS_STRIDE + row] = v.x;
      xs[(k4 + 1) * XS_STRIDE + row] = v.y;
      xs[(k4 + 2) * XS_STRIDE + row] = v.z;
      xs[(k4 + 3) * XS_STRIDE + row] = v.w;
    }
  }
  __syncthreads();

  float acc[8][4];
#pragma unroll
  for (int i = 0; i < 8; ++i)
#pragma unroll
    for (int j = 0; j < 4; ++j) acc[i][j] = 0.f;

#pragma unroll 4
  for (int k = 0; k < F1; ++k) {
    float4 w = *reinterpret_cast<const float4*>(&W1[k * F1 + 4 * cg]);
    float4 xa = *reinterpret_cast<const float4*>(&xs[k * XS_STRIDE + rg * 8]);
    float4 xb = *reinterpret_cast<const float4*>(&xs[k * XS_STRIDE + rg * 8 + 4]);
    const float xr[8] = {xa.x, xa.y, xa.z, xa.w, xb.x, xb.y, xb.z, xb.w};
#pragma unroll
    for (int i = 0; i < 8; ++i) {
      acc[i][0] = fmaf(xr[i], w.x, acc[i][0]);
      acc[i][1] = fmaf(xr[i], w.y, acc[i][1]);
      acc[i][2] = fmaf(xr[i], w.z, acc[i][2]);
      acc[i][3] = fmaf(xr[i], w.w, acc[i][3]);
    }
  }

  float4 as4 = *reinterpret_cast<const float4*>(&as[4 * cg]);
  float4 ad4 = *reinterpret_cast<const float4*>(&ad[4 * cg]);
  int h = cg >> 2;
#pragma unroll
  for (int i = 0; i < 8; ++i) {
    int row = r0 + rg * 8 + i;
    bool act = row < N;
    if (act) {
      uint2 pk;
      pk.x = (uint)f2bf(acc[i][0]) | ((uint)f2bf(acc[i][1]) << 16);
      pk.y = (uint)f2bf(acc[i][2]) | ((uint)f2bf(acc[i][3]) << 16);
      *reinterpret_cast<uint2*>(&h1b[(size_t)row * 64 + 2 * cg]) = pk;
    }
    float ps = acc[i][0] * as4.x + acc[i][1] * as4.y + acc[i][2] * as4.z + acc[i][3] * as4.w;
    float pd = acc[i][0] * ad4.x + acc[i][1] * ad4.y + acc[i][2] * ad4.z + acc[i][3] * ad4.w;
    ps += __shfl_xor(ps, 1); ps += __shfl_xor(ps, 2);
    pd += __shfl_xor(pd, 1); pd += __shfl_xor(pd, 2);
    if (act && (cg & 3) == 0) {
      a_src[row * HEADS + h] = ps;
      a_dst[row * HEADS + h] = pd;
    }
  }
}

// ---------------- layer 1 aggregate (single pass, no stats) ----------------
// 1 wave/dst; thread c owns channels {2c,2c+1}, head c>>3.
// No max-subtraction (scores bounded); numerator+denominator in one pass.
// Two independent edge chains (stride 2) + unroll -> 4 gathers in flight.
__global__ void k_agg1(const int* __restrict__ off, const int* __restrict__ csr,
                       const uint* __restrict__ h1b, const float* __restrict__ a_src,
                       const float* __restrict__ a_dst, const float* __restrict__ b1,
                       float* __restrict__ out1, int N) {
  int w = threadIdx.x >> 6, c = threadIdx.x & 63, h = c >> 3;
  int d = blockIdx.x * 4 + w;
  if (d >= N) return;
  int beg = off[d], end = off[d + 1];
  float adl = a_dst[d * HEADS + h];
  float aA0 = 0.f, aA1 = 0.f, dA = 0.f;
  float aB0 = 0.f, aB1 = 0.f, dB = 0.f;
  int j = beg;
#pragma unroll 2
  for (; j + 1 < end; j += 2) {
    int sA = csr[j], sB = csr[j + 1];
    float vA = a_src[sA * HEADS + h] + adl;
    float vB = a_src[sB * HEADS + h] + adl;
    vA = vA >= 0.f ? vA : 0.2f * vA;
    vB = vB >= 0.f ? vB : 0.2f * vB;
    float pA = __expf(vA), pB = __expf(vB);
    uint wA = h1b[(size_t)sA * 64 + c];
    uint wB = h1b[(size_t)sB * 64 + c];
    aA0 = fmaf(pA, bf2f_lo(wA), aA0); aA1 = fmaf(pA, bf2f_hi(wA), aA1); dA += pA;
    aB0 = fmaf(pB, bf2f_lo(wB), aB0); aB1 = fmaf(pB, bf2f_hi(wB), aB1); dB += pB;
  }
  if (j < end) {
    int s = csr[j];
    float v = a_src[s * HEADS + h] + adl;
    v = v >= 0.f ? v : 0.2f * v;
    float p = __expf(v);
    uint wd = h1b[(size_t)s * 64 + c];
    aA0 = fmaf(p, bf2f_lo(wd), aA0); aA1 = fmaf(p, bf2f_hi(wd), aA1); dA += p;
  }
  float inv = 1.f / (dA + dB);   // self-loop guarantees den > 0
  float2 o;
  o.x = (aA0 + aB0) * inv + b1[2 * c];
  o.y = (aA1 + aB1) * inv + b1[2 * c + 1];
  *reinterpret_cast<float2*>(&out1[(size_t)d * F1 + 2 * c]) = o;
}

// ---------------- layer 2 GEMM ----------------
// 64 rows x 64 cols per block; 256 threads; thread owns 4 rows x 4 cols.
__global__ __launch_bounds__(256) void k_gemm2(
    const float* __restrict__ out1, const float* __restrict__ W2,
    const float* __restrict__ as2, const float* __restrict__ ad2,
    uint* __restrict__ h2b, float* __restrict__ a_src2,
    float* __restrict__ a_dst2, int N) {
  __shared__ float xs[F1 * XS_STRIDE];   // xs[k][row]
  int tx = threadIdx.x;
  int cg = tx & 15;          // cols 4cg..4cg+3
  int rg = tx >> 4;          // rows 4rg..4rg+3
  int r0 = blockIdx.x * 64;

  {
    int row = tx & 63, kq0 = tx >> 6;
#pragma unroll
    for (int it = 0; it < 8; ++it) {
      int k4 = (it * 4 + kq0) * 4;
      float4 v = make_float4(0.f, 0.f, 0.f, 0.f);
      if (r0 + row < N) v = *reinterpret_cast<const float4*>(&out1[(size_t)(r0 + row) * F1 + k4]);
      v.x = v.x > 0.f ? v.x : __expf(v.x) - 1.f;
      v.y = v.y > 0.f ? v.y : __expf(v.y) - 1.f;
      v.z = v.z > 0.f ? v.z : __expf(v.z) - 1.f;
      v.w = v.w > 0.f ? v.w : __expf(v.w) - 1.f;
      xs[(k4 + 0) * XS_STRIDE + row] = v.x;
      xs[(k4 + 1) * XS_STRIDE + row] = v.y;
      xs[(k4 + 2) * XS_STRIDE + row] = v.z;
      xs[(k4 + 3) * XS_STRIDE + row] = v.w;
    }
  }
  __syncthreads();

  float acc[4][4];
#pragma unroll
  for (int i = 0; i < 4; ++i)
#pragma unroll
    for (int j = 0; j < 4; ++j) acc[i][j] = 0.f;

#pragma unroll 4
  for (int k = 0; k < F1; ++k) {
    float4 w = *reinterpret_cast<const float4*>(&W2[k * OUTD + 4 * cg]);
    float4 xa = *reinterpret_cast<const float4*>(&xs[k * XS_STRIDE + rg * 4]);
    const float xr[4] = {xa.x, xa.y, xa.z, xa.w};
#pragma unroll
    for (int i = 0; i < 4; ++i) {
      acc[i][0] = fmaf(xr[i], w.x, acc[i][0]);
      acc[i][1] = fmaf(xr[i], w.y, acc[i][1]);
      acc[i][2] = fmaf(xr[i], w.z, acc[i][2]);
      acc[i][3] = fmaf(xr[i], w.w, acc[i][3]);
    }
  }

  float4 as4 = *reinterpret_cast<const float4*>(&as2[4 * cg]);
  float4 ad4 = *reinterpret_cast<const float4*>(&ad2[4 * cg]);
#pragma unroll
  for (int i = 0; i < 4; ++i) {
    int row = r0 + rg * 4 + i;
    bool act = row < N;
    if (act) {
      uint2 pk;
      pk.x = (uint)f2bf(acc[i][0]) | ((uint)f2bf(acc[i][1]) << 16);
      pk.y = (uint)f2bf(acc[i][2]) | ((uint)f2bf(acc[i][3]) << 16);
      *reinterpret_cast<uint2*>(&h2b[(size_t)row * 32 + 2 * cg]) = pk;
    }
    float ps = acc[i][0] * as4.x + acc[i][1] * as4.y + acc[i][2] * as4.z + acc[i][3] * as4.w;
    float pd = acc[i][0] * ad4.x + acc[i][1] * ad4.y + acc[i][2] * ad4.z + acc[i][3] * ad4.w;
    ps += __shfl_xor(ps, 1); ps += __shfl_xor(ps, 2);
    ps += __shfl_xor(ps, 4); ps += __shfl_xor(ps, 8);
    pd += __shfl_xor(pd, 1); pd += __shfl_xor(pd, 2);
    pd += __shfl_xor(pd, 4); pd += __shfl_xor(pd, 8);
    if (act && cg == 0) {
      a_src2[row] = ps;
      a_dst2[row] = pd;
    }
  }
}

// ---------------- layer 2 aggregate (single pass, no stats) ----------------
// 1 wave/dst; two 32-lane halves process alternating edges; lane owns 2 channels
// via uint loads; halves combined with shfl_xor(32).
__global__ void k_agg2(const int* __restrict__ off, const int* __restrict__ csr,
                       const uint* __restrict__ h2b, const float* __restrict__ a_src2,
                       const float* __restrict__ a_dst2, const float* __restrict__ b2,
                       float* __restrict__ out, int N) {
  int w = threadIdx.x >> 6, lane = threadIdx.x & 63;
  int half = lane >> 5, c = lane & 31;
  int d = blockIdx.x * 4 + w;
  if (d >= N) return;
  int beg = off[d], end = off[d + 1];
  float adl = a_dst2[d];
  float acc0 = 0.f, acc1 = 0.f, den = 0.f;
#pragma unroll 2
  for (int j = beg + half; j < end; j += 2) {
    int s = csr[j];
    float v = a_src2[s] + adl;
    v = v >= 0.f ? v : 0.2f * v;
    float p = __expf(v);
    uint wd = h2b[(size_t)s * 32 + c];
    acc0 = fmaf(p, bf2f_lo(wd), acc0);
    acc1 = fmaf(p, bf2f_hi(wd), acc1);
    den += p;
  }
  acc0 += __shfl_xor(acc0, 32);
  acc1 += __shfl_xor(acc1, 32);
  den  += __shfl_xor(den, 32);
  if (half == 0) {
    float inv = 1.f / den;
    float2 o;
    o.x = acc0 * inv + b2[2 * c];
    o.y = acc1 * inv + b2[2 * c + 1];
    *reinterpret_cast<float2*>(&out[(size_t)d * OUTD + 2 * c]) = o;
  }
}

extern "C" void kernel_launch(void* const* d_in, const int* in_sizes, int n_in,
                              void* d_out, int out_size, void* d_ws, size_t ws_size,
                              hipStream_t stream) {
  const float* x   = (const float*)d_in[0];
  const int*   ei  = (const int*)d_in[1];
  const float* W1  = (const float*)d_in[2];
  const float* as1 = (const float*)d_in[3];
  const float* ad1 = (const float*)d_in[4];
  const float* b1  = (const float*)d_in[5];
  const float* W2  = (const float*)d_in[6];
  const float* as2 = (const float*)d_in[7];
  const float* ad2 = (const float*)d_in[8];
  const float* b2  = (const float*)d_in[9];
  float* out = (float*)d_out;

  int N = in_sizes[0] / F1;
  int E = in_sizes[1] / 2;
  int ET = E + N;
  int NB = (N + SCANB - 1) / SCANB;
  int NT = (N + 63) / 64;   // GEMM tiles

  // workspace layout
  char* p = (char*)d_ws;
  int* deg    = (int*)p;            p += (size_t)N * 4;
  int* off    = (int*)p;            p += (size_t)(N + 1) * 4;
  int* cursor = (int*)p;            p += (size_t)N * 4;
  int* bsum   = (int*)p;            p += (size_t)SCANB * 4;
  int* csr    = (int*)p;            p += (size_t)ET * 4;
  uint* h1b     = (uint*)p;         p += (size_t)N * 64 * 4;
  float* out1   = (float*)p;        p += (size_t)N * F1 * 4;
  float* a_src1 = (float*)p;        p += (size_t)N * HEADS * 4;
  float* a_dst1 = (float*)p;        p += (size_t)N * HEADS * 4;
  // layer-2 aliases over dead layer-1 regions
  uint* h2b     = h1b;              // N*32 uint (h1b dead after k_agg1)
  float* a_src2 = a_src1;           // N
  float* a_dst2 = a_dst1;           // N

  // CSR build (shared by both layers)
  hipLaunchKernelGGL(k_zero,  dim3((N + 255) / 256), dim3(256), 0, stream, deg, N);
  hipLaunchKernelGGL(k_count, dim3((ET + 255) / 256), dim3(256), 0, stream, ei, E, N, deg);
  hipLaunchKernelGGL(k_scan1, dim3(NB), dim3(SCANB), 0, stream, deg, N, off, bsum);
  hipLaunchKernelGGL(k_scan2, dim3(1), dim3(SCANB), 0, stream, bsum, NB);
  hipLaunchKernelGGL(k_scan3, dim3(NB), dim3(SCANB), 0, stream, off, cursor, deg, bsum, N);
  hipLaunchKernelGGL(k_fill,  dim3((ET + 255) / 256), dim3(256), 0, stream, ei, E, N, cursor, csr);

  // layer 1
  hipLaunchKernelGGL(k_gemm1, dim3(NT), dim3(256), 0, stream,
                     x, W1, as1, ad1, h1b, a_src1, a_dst1, N);
  hipLaunchKernelGGL(k_agg1, dim3((N + 3) / 4), dim3(256), 0, stream,
                     off, csr, h1b, a_src1, a_dst1, b1, out1, N);

  // layer 2
  hipLaunchKernelGGL(k_gemm2, dim3(NT), dim3(256), 0, stream,
                     out1, W2, as2, ad2, h2b, a_src2, a_dst2, N);
  hipLaunchKernelGGL(k_agg2, dim3((N + 3) / 4), dim3(256), 0, stream,
                     off, csr, h2b, a_src2, a_dst2, b2, out, N);
}

// Round 6
// 194.668 us; speedup vs baseline: 7.3322x; 1.3081x over previous
//
#include <hip/hip_runtime.h>
#include <hip/hip_bf16.h>

#define HEADS 8
#define HID 16
#define F1 128    // HEADS*HID
#define OUTD 64
#define XS_STRIDE 68   // padded LDS stride: 16B-aligned rows (68*4=272=17*16)
#define BWL 7          // log2(bucket width)
#define BW 128         // dst-range per bucket
#define MAXBUK 512     // >= ceil(N/BW); N=50000 -> 391
#define CHUNK 4096     // edges per block in count/scatter (256 thr x 16)

typedef unsigned int uint;
typedef unsigned short ushort;

__device__ __forceinline__ ushort f2bf(float f) {
  __hip_bfloat16 b = __float2bfloat16(f);
  return *reinterpret_cast<ushort*>(&b);
}
__device__ __forceinline__ float bf2f_lo(uint w) {
  return __uint_as_float((w & 0xFFFFu) << 16);
}
__device__ __forceinline__ float bf2f_hi(uint w) {
  return __uint_as_float(w & 0xFFFF0000u);
}

// ---------------- CSR build (bucket radix, low write-amplification) ----------------

__global__ void k_z(int* __restrict__ a, int n) {
  int i = blockIdx.x * blockDim.x + threadIdx.x;
  if (i < n) a[i] = 0;
}

// Pass A: coarse histogram of dst>>7 via LDS, then per-block global adds.
__global__ __launch_bounds__(256) void k_bukcount(const int* __restrict__ ei, int E, int N,
                                                  int* __restrict__ bukcnt) {
  __shared__ int hist[MAXBUK];
  int t = threadIdx.x;
  hist[t] = 0; hist[t + 256] = 0;
  __syncthreads();
  long long e0 = (long long)blockIdx.x * CHUNK;
  int ET = E + N;
#pragma unroll
  for (int i = 0; i < 16; ++i) {
    long long e = e0 + i * 256 + t;
    if (e < ET) {
      int d = e < E ? ei[E + e] : (int)(e - E);
      atomicAdd(&hist[d >> BWL], 1);
    }
  }
  __syncthreads();
  for (int b = t; b < MAXBUK; b += 256)
    if (hist[b]) atomicAdd(&bukcnt[b], hist[b]);
}

// scan bucket counts (NBUK <= 512) -> bases & cursors; off[N]=ET.
__global__ __launch_bounds__(512) void k_bukscan(const int* __restrict__ bukcnt,
                                                 int* __restrict__ bukbase,
                                                 int* __restrict__ bukcur,
                                                 int* __restrict__ off,
                                                 int NBUK, int N, int ET) {
  __shared__ int sm[512];
  int t = threadIdx.x;
  int v = t < NBUK ? bukcnt[t] : 0;
  sm[t] = v;
  __syncthreads();
  for (int o = 1; o < 512; o <<= 1) {
    int u = t >= o ? sm[t - o] : 0;
    __syncthreads();
    sm[t] += u;
    __syncthreads();
  }
  if (t < NBUK) {
    int base = sm[t] - v;   // exclusive
    bukbase[t] = base;
    bukcur[t] = base;
  }
  if (t == 0) { bukbase[NBUK] = ET; off[N] = ET; }
}

// Pass B: scatter (src,dst) pairs into bucket-major storage; per-block
// contiguous runs reserved with one global atomic per touched bucket.
__global__ __launch_bounds__(256) void k_scatter(const int* __restrict__ ei, int E, int N,
                                                 int* __restrict__ bukcur,
                                                 int2* __restrict__ pairs) {
  __shared__ int hist[MAXBUK];
  int t = threadIdx.x;
  hist[t] = 0; hist[t + 256] = 0;
  __syncthreads();
  long long e0 = (long long)blockIdx.x * CHUNK;
  int ET = E + N;
  int myS[16], myD[16];
#pragma unroll
  for (int i = 0; i < 16; ++i) {
    long long e = e0 + i * 256 + t;
    if (e < ET) {
      int s = e < E ? ei[e] : (int)(e - E);
      int d = e < E ? ei[E + e] : (int)(e - E);
      myS[i] = s; myD[i] = d;
      atomicAdd(&hist[d >> BWL], 1);
    } else {
      myD[i] = -1;
    }
  }
  __syncthreads();
  // reserve a contiguous run per bucket; hist becomes the LDS write cursor
  for (int b = t; b < MAXBUK; b += 256) {
    int c = hist[b];
    hist[b] = c ? atomicAdd(&bukcur[b], c) : 0;
  }
  __syncthreads();
#pragma unroll
  for (int i = 0; i < 16; ++i) {
    if (myD[i] >= 0) {
      int pos = atomicAdd(&hist[myD[i] >> BWL], 1);
      pairs[pos] = make_int2(myS[i], myD[i]);
    }
  }
}

// Pass C: per-bucket fine CSR: LDS count over 128 dsts, scan, write off[] and csr[].
__global__ __launch_bounds__(256) void k_csr(const int2* __restrict__ pairs,
                                             const int* __restrict__ bukbase,
                                             int* __restrict__ off, int* __restrict__ csr,
                                             int N) {
  __shared__ int cnt[BW];
  __shared__ int cur[BW];
  int b = blockIdx.x, t = threadIdx.x;
  int beg = bukbase[b], end = bukbase[b + 1];
  if (t < BW) cnt[t] = 0;
  __syncthreads();
  for (int j = beg + t; j < end; j += 256)
    atomicAdd(&cnt[pairs[j].y & (BW - 1)], 1);
  __syncthreads();
  int my = t < BW ? cnt[t] : 0;
  for (int o = 1; o < BW; o <<= 1) {
    int v = (t < BW && t >= o) ? cnt[t - o] : 0;
    __syncthreads();
    if (t < BW) cnt[t] += v;
    __syncthreads();
  }
  if (t < BW) {
    int start = beg + cnt[t] - my;   // exclusive within bucket
    cur[t] = start;
    int d0 = b * BW + t;
    if (d0 < N) off[d0] = start;
  }
  __syncthreads();
  for (int j = beg + t; j < end; j += 256) {
    int2 pr = pairs[j];
    int pos = atomicAdd(&cur[pr.y & (BW - 1)], 1);
    csr[pos] = pr.x;
  }
}

// ---------------- layer 1 GEMM ----------------
// 64 rows x 128 cols per block; 256 threads; thread owns 8 rows x 4 cols.
__global__ __launch_bounds__(256) void k_gemm1(
    const float* __restrict__ x, const float* __restrict__ W1,
    const float* __restrict__ as, const float* __restrict__ ad,
    uint* __restrict__ h1b, float* __restrict__ a_src,
    float* __restrict__ a_dst, int N) {
  __shared__ float xs[F1 * XS_STRIDE];   // xs[k][row], 34 KB
  int tx = threadIdx.x;
  int cg = tx & 31;          // col group: cols 4cg..4cg+3
  int rg = tx >> 5;          // row group: rows 8rg..8rg+7
  int r0 = blockIdx.x * 64;

  {
    int row = tx & 63, kq0 = tx >> 6;   // kq0 in [0,4)
#pragma unroll
    for (int it = 0; it < 8; ++it) {
      int k4 = (it * 4 + kq0) * 4;
      float4 v = make_float4(0.f, 0.f, 0.f, 0.f);
      if (r0 + row < N) v = *reinterpret_cast<const float4*>(&x[(size_t)(r0 + row) * F1 + k4]);
      xs[(k4 + 0) * XS_STRIDE + row] = v.x;
      xs[(k4 + 1) * XS_STRIDE + row] = v.y;
      xs[(k4 + 2) * XS_STRIDE + row] = v.z;
      xs[(k4 + 3) * XS_STRIDE + row] = v.w;
    }
  }
  __syncthreads();

  float acc[8][4];
#pragma unroll
  for (int i = 0; i < 8; ++i)
#pragma unroll
    for (int j = 0; j < 4; ++j) acc[i][j] = 0.f;

#pragma unroll 4
  for (int k = 0; k < F1; ++k) {
    float4 w = *reinterpret_cast<const float4*>(&W1[k * F1 + 4 * cg]);
    float4 xa = *reinterpret_cast<const float4*>(&xs[k * XS_STRIDE + rg * 8]);
    float4 xb = *reinterpret_cast<const float4*>(&xs[k * XS_STRIDE + rg * 8 + 4]);
    const float xr[8] = {xa.x, xa.y, xa.z, xa.w, xb.x, xb.y, xb.z, xb.w};
#pragma unroll
    for (int i = 0; i < 8; ++i) {
      acc[i][0] = fmaf(xr[i], w.x, acc[i][0]);
      acc[i][1] = fmaf(xr[i], w.y, acc[i][1]);
      acc[i][2] = fmaf(xr[i], w.z, acc[i][2]);
      acc[i][3] = fmaf(xr[i], w.w, acc[i][3]);
    }
  }

  float4 as4 = *reinterpret_cast<const float4*>(&as[4 * cg]);
  float4 ad4 = *reinterpret_cast<const float4*>(&ad[4 * cg]);
  int h = cg >> 2;
#pragma unroll
  for (int i = 0; i < 8; ++i) {
    int row = r0 + rg * 8 + i;
    bool act = row < N;
    if (act) {
      uint2 pk;
      pk.x = (uint)f2bf(acc[i][0]) | ((uint)f2bf(acc[i][1]) << 16);
      pk.y = (uint)f2bf(acc[i][2]) | ((uint)f2bf(acc[i][3]) << 16);
      *reinterpret_cast<uint2*>(&h1b[(size_t)row * 64 + 2 * cg]) = pk;
    }
    float ps = acc[i][0] * as4.x + acc[i][1] * as4.y + acc[i][2] * as4.z + acc[i][3] * as4.w;
    float pd = acc[i][0] * ad4.x + acc[i][1] * ad4.y + acc[i][2] * ad4.z + acc[i][3] * ad4.w;
    ps += __shfl_xor(ps, 1); ps += __shfl_xor(ps, 2);
    pd += __shfl_xor(pd, 1); pd += __shfl_xor(pd, 2);
    if (act && (cg & 3) == 0) {
      a_src[row * HEADS + h] = ps;
      a_dst[row * HEADS + h] = pd;
    }
  }
}

// ---------------- layer 1 aggregate ----------------
__global__ void k_agg1(const int* __restrict__ off, const int* __restrict__ csr,
                       const uint* __restrict__ h1b, const float* __restrict__ a_src,
                       const float* __restrict__ a_dst, const float* __restrict__ b1,
                       float* __restrict__ out1, int N) {
  int w = threadIdx.x >> 6, c = threadIdx.x & 63, h = c >> 3;
  int d = blockIdx.x * 4 + w;
  if (d >= N) return;
  int beg = off[d], end = off[d + 1];
  float adl = a_dst[d * HEADS + h];
  float aA0 = 0.f, aA1 = 0.f, dA = 0.f;
  float aB0 = 0.f, aB1 = 0.f, dB = 0.f;
  int j = beg;
#pragma unroll 2
  for (; j + 1 < end; j += 2) {
    int sA = csr[j], sB = csr[j + 1];
    float vA = a_src[sA * HEADS + h] + adl;
    float vB = a_src[sB * HEADS + h] + adl;
    vA = vA >= 0.f ? vA : 0.2f * vA;
    vB = vB >= 0.f ? vB : 0.2f * vB;
    float pA = __expf(vA), pB = __expf(vB);
    uint wA = h1b[(size_t)sA * 64 + c];
    uint wB = h1b[(size_t)sB * 64 + c];
    aA0 = fmaf(pA, bf2f_lo(wA), aA0); aA1 = fmaf(pA, bf2f_hi(wA), aA1); dA += pA;
    aB0 = fmaf(pB, bf2f_lo(wB), aB0); aB1 = fmaf(pB, bf2f_hi(wB), aB1); dB += pB;
  }
  if (j < end) {
    int s = csr[j];
    float v = a_src[s * HEADS + h] + adl;
    v = v >= 0.f ? v : 0.2f * v;
    float p = __expf(v);
    uint wd = h1b[(size_t)s * 64 + c];
    aA0 = fmaf(p, bf2f_lo(wd), aA0); aA1 = fmaf(p, bf2f_hi(wd), aA1); dA += p;
  }
  float inv = 1.f / (dA + dB);   // self-loop guarantees den > 0
  float2 o;
  o.x = (aA0 + aB0) * inv + b1[2 * c];
  o.y = (aA1 + aB1) * inv + b1[2 * c + 1];
  *reinterpret_cast<float2*>(&out1[(size_t)d * F1 + 2 * c]) = o;
}

// ---------------- layer 2 GEMM ----------------
__global__ __launch_bounds__(256) void k_gemm2(
    const float* __restrict__ out1, const float* __restrict__ W2,
    const float* __restrict__ as2, const float* __restrict__ ad2,
    uint* __restrict__ h2b, float* __restrict__ a_src2,
    float* __restrict__ a_dst2, int N) {
  __shared__ float xs[F1 * XS_STRIDE];   // xs[k][row]
  int tx = threadIdx.x;
  int cg = tx & 15;          // cols 4cg..4cg+3
  int rg = tx >> 4;          // rows 4rg..4rg+3
  int r0 = blockIdx.x * 64;

  {
    int row = tx & 63, kq0 = tx >> 6;
#pragma unroll
    for (int it = 0; it < 8; ++it) {
      int k4 = (it * 4 + kq0) * 4;
      float4 v = make_float4(0.f, 0.f, 0.f, 0.f);
      if (r0 + row < N) v = *reinterpret_cast<const float4*>(&out1[(size_t)(r0 + row) * F1 + k4]);
      v.x = v.x > 0.f ? v.x : __expf(v.x) - 1.f;
      v.y = v.y > 0.f ? v.y : __expf(v.y) - 1.f;
      v.z = v.z > 0.f ? v.z : __expf(v.z) - 1.f;
      v.w = v.w > 0.f ? v.w : __expf(v.w) - 1.f;
      xs[(k4 + 0) * XS_STRIDE + row] = v.x;
      xs[(k4 + 1) * XS_STRIDE + row] = v.y;
      xs[(k4 + 2) * XS_STRIDE + row] = v.z;
      xs[(k4 + 3) * XS_STRIDE + row] = v.w;
    }
  }
  __syncthreads();

  float acc[4][4];
#pragma unroll
  for (int i = 0; i < 4; ++i)
#pragma unroll
    for (int j = 0; j < 4; ++j) acc[i][j] = 0.f;

#pragma unroll 4
  for (int k = 0; k < F1; ++k) {
    float4 w = *reinterpret_cast<const float4*>(&W2[k * OUTD + 4 * cg]);
    float4 xa = *reinterpret_cast<const float4*>(&xs[k * XS_STRIDE + rg * 4]);
    const float xr[4] = {xa.x, xa.y, xa.z, xa.w};
#pragma unroll
    for (int i = 0; i < 4; ++i) {
      acc[i][0] = fmaf(xr[i], w.x, acc[i][0]);
      acc[i][1] = fmaf(xr[i], w.y, acc[i][1]);
      acc[i][2] = fmaf(xr[i], w.z, acc[i][2]);
      acc[i][3] = fmaf(xr[i], w.w, acc[i][3]);
    }
  }

  float4 as4 = *reinterpret_cast<const float4*>(&as2[4 * cg]);
  float4 ad4 = *reinterpret_cast<const float4*>(&ad2[4 * cg]);
#pragma unroll
  for (int i = 0; i < 4; ++i) {
    int row = r0 + rg * 4 + i;
    bool act = row < N;
    if (act) {
      uint2 pk;
      pk.x = (uint)f2bf(acc[i][0]) | ((uint)f2bf(acc[i][1]) << 16);
      pk.y = (uint)f2bf(acc[i][2]) | ((uint)f2bf(acc[i][3]) << 16);
      *reinterpret_cast<uint2*>(&h2b[(size_t)row * 32 + 2 * cg]) = pk;
    }
    float ps = acc[i][0] * as4.x + acc[i][1] * as4.y + acc[i][2] * as4.z + acc[i][3] * as4.w;
    float pd = acc[i][0] * ad4.x + acc[i][1] * ad4.y + acc[i][2] * ad4.z + acc[i][3] * ad4.w;
    ps += __shfl_xor(ps, 1); ps += __shfl_xor(ps, 2);
    ps += __shfl_xor(ps, 4); ps += __shfl_xor(ps, 8);
    pd += __shfl_xor(pd, 1); pd += __shfl_xor(pd, 2);
    pd += __shfl_xor(pd, 4); pd += __shfl_xor(pd, 8);
    if (act && cg == 0) {
      a_src2[row] = ps;
      a_dst2[row] = pd;
    }
  }
}

// ---------------- layer 2 aggregate ----------------
__global__ void k_agg2(const int* __restrict__ off, const int* __restrict__ csr,
                       const uint* __restrict__ h2b, const float* __restrict__ a_src2,
                       const float* __restrict__ a_dst2, const float* __restrict__ b2,
                       float* __restrict__ out, int N) {
  int w = threadIdx.x >> 6, lane = threadIdx.x & 63;
  int half = lane >> 5, c = lane & 31;
  int d = blockIdx.x * 4 + w;
  if (d >= N) return;
  int beg = off[d], end = off[d + 1];
  float adl = a_dst2[d];
  float acc0 = 0.f, acc1 = 0.f, den = 0.f;
#pragma unroll 2
  for (int j = beg + half; j < end; j += 2) {
    int s = csr[j];
    float v = a_src2[s] + adl;
    v = v >= 0.f ? v : 0.2f * v;
    float p = __expf(v);
    uint wd = h2b[(size_t)s * 32 + c];
    acc0 = fmaf(p, bf2f_lo(wd), acc0);
    acc1 = fmaf(p, bf2f_hi(wd), acc1);
    den += p;
  }
  acc0 += __shfl_xor(acc0, 32);
  acc1 += __shfl_xor(acc1, 32);
  den  += __shfl_xor(den, 32);
  if (half == 0) {
    float inv = 1.f / den;
    float2 o;
    o.x = acc0 * inv + b2[2 * c];
    o.y = acc1 * inv + b2[2 * c + 1];
    *reinterpret_cast<float2*>(&out[(size_t)d * OUTD + 2 * c]) = o;
  }
}

extern "C" void kernel_launch(void* const* d_in, const int* in_sizes, int n_in,
                              void* d_out, int out_size, void* d_ws, size_t ws_size,
                              hipStream_t stream) {
  const float* x   = (const float*)d_in[0];
  const int*   ei  = (const int*)d_in[1];
  const float* W1  = (const float*)d_in[2];
  const float* as1 = (const float*)d_in[3];
  const float* ad1 = (const float*)d_in[4];
  const float* b1  = (const float*)d_in[5];
  const float* W2  = (const float*)d_in[6];
  const float* as2 = (const float*)d_in[7];
  const float* ad2 = (const float*)d_in[8];
  const float* b2  = (const float*)d_in[9];
  float* out = (float*)d_out;

  int N = in_sizes[0] / F1;
  int E = in_sizes[1] / 2;
  int ET = E + N;
  int NBUK = (N + BW - 1) / BW;       // 391 for N=50000 (<= MAXBUK)
  int NCH = (ET + CHUNK - 1) / CHUNK; // count/scatter blocks
  int NT = (N + 63) / 64;             // GEMM tiles

  // workspace layout (16B-aligned chunks)
  char* p = (char*)d_ws;
  auto alloc = [&](size_t bytes) {
    char* q = p;
    p += (bytes + 15) & ~(size_t)15;
    return q;
  };
  int* bukcnt  = (int*)alloc((size_t)NBUK * 4);
  int* bukbase = (int*)alloc((size_t)(NBUK + 1) * 4);
  int* bukcur  = (int*)alloc((size_t)NBUK * 4);
  int* off     = (int*)alloc((size_t)(N + 1) * 4);
  int2* pairs  = (int2*)alloc((size_t)ET * 8);
  int* csr     = (int*)alloc((size_t)ET * 4);
  uint* h1b    = (uint*)alloc((size_t)N * 64 * 4);
  float* out1  = (float*)alloc((size_t)N * F1 * 4);
  float* a_src1 = (float*)alloc((size_t)N * HEADS * 4);
  float* a_dst1 = (float*)alloc((size_t)N * HEADS * 4);
  // layer-2 aliases over dead layer-1 regions
  uint* h2b     = h1b;              // N*32 uint (h1b dead after k_agg1)
  float* a_src2 = a_src1;           // N
  float* a_dst2 = a_dst1;           // N

  // CSR build (shared by both layers)
  hipLaunchKernelGGL(k_z, dim3((NBUK + 255) / 256), dim3(256), 0, stream, bukcnt, NBUK);
  hipLaunchKernelGGL(k_bukcount, dim3(NCH), dim3(256), 0, stream, ei, E, N, bukcnt);
  hipLaunchKernelGGL(k_bukscan, dim3(1), dim3(512), 0, stream,
                     bukcnt, bukbase, bukcur, off, NBUK, N, ET);
  hipLaunchKernelGGL(k_scatter, dim3(NCH), dim3(256), 0, stream, ei, E, N, bukcur, pairs);
  hipLaunchKernelGGL(k_csr, dim3(NBUK), dim3(256), 0, stream, pairs, bukbase, off, csr, N);

  // layer 1
  hipLaunchKernelGGL(k_gemm1, dim3(NT), dim3(256), 0, stream,
                     x, W1, as1, ad1, h1b, a_src1, a_dst1, N);
  hipLaunchKernelGGL(k_agg1, dim3((N + 3) / 4), dim3(256), 0, stream,
                     off, csr, h1b, a_src1, a_dst1, b1, out1, N);

  // layer 2
  hipLaunchKernelGGL(k_gemm2, dim3(NT), dim3(256), 0, stream,
                     out1, W2, as2, ad2, h2b, a_src2, a_dst2, N);
  hipLaunchKernelGGL(k_agg2, dim3((N + 3) / 4), dim3(256), 0, stream,
                     off, csr, h2b, a_src2, a_dst2, b2, out, N);
}

// Round 7
// 186.433 us; speedup vs baseline: 7.6561x; 1.0442x over previous
//
#include <hip/hip_runtime.h>
#include <hip/hip_bf16.h>

#define HEADS 8
#define HID 16
#define F1 128    // HEADS*HID
#define OUTD 64
#define XS_STRIDE 68   // padded LDS stride: 16B-aligned rows (68*4=272=17*16)
#define BWL 7          // log2(bucket width)
#define BW 128         // dst-range per bucket
#define MAXBUK 512     // >= ceil(N/BW); N=50000 -> 391
#define CHUNK 4096     // edges per block in count/scatter (256 thr x 16)

typedef unsigned int uint;
typedef unsigned short ushort;

__device__ __forceinline__ ushort f2bf(float f) {
  __hip_bfloat16 b = __float2bfloat16(f);
  return *reinterpret_cast<ushort*>(&b);
}
__device__ __forceinline__ float bf2f_lo(uint w) {
  return __uint_as_float((w & 0xFFFFu) << 16);
}
__device__ __forceinline__ float bf2f_hi(uint w) {
  return __uint_as_float(w & 0xFFFF0000u);
}

// ---------------- CSR build (bucket radix, low write-amplification) ----------------
// pairs packed: src in bits [0,20), dst&(BW-1) in bits [20,27). Requires N < 2^20.

__global__ void k_z(int* __restrict__ a, int n) {
  int i = blockIdx.x * blockDim.x + threadIdx.x;
  if (i < n) a[i] = 0;
}

// Pass A: coarse histogram of dst>>7 via LDS, then per-block global adds.
__global__ __launch_bounds__(256) void k_bukcount(const int* __restrict__ ei, int E, int N,
                                                  int* __restrict__ bukcnt) {
  __shared__ int hist[MAXBUK];
  int t = threadIdx.x;
  hist[t] = 0; hist[t + 256] = 0;
  __syncthreads();
  long long e0 = (long long)blockIdx.x * CHUNK;
  int ET = E + N;
#pragma unroll
  for (int i = 0; i < 16; ++i) {
    long long e = e0 + i * 256 + t;
    if (e < ET) {
      int d = e < E ? ei[E + e] : (int)(e - E);
      atomicAdd(&hist[d >> BWL], 1);
    }
  }
  __syncthreads();
  for (int b = t; b < MAXBUK; b += 256)
    if (hist[b]) atomicAdd(&bukcnt[b], hist[b]);
}

// scan bucket counts (NBUK <= 512) -> bases & cursors; off[N]=ET.
__global__ __launch_bounds__(512) void k_bukscan(const int* __restrict__ bukcnt,
                                                 int* __restrict__ bukbase,
                                                 int* __restrict__ bukcur,
                                                 int* __restrict__ off,
                                                 int NBUK, int N, int ET) {
  __shared__ int sm[512];
  int t = threadIdx.x;
  int v = t < NBUK ? bukcnt[t] : 0;
  sm[t] = v;
  __syncthreads();
  for (int o = 1; o < 512; o <<= 1) {
    int u = t >= o ? sm[t - o] : 0;
    __syncthreads();
    sm[t] += u;
    __syncthreads();
  }
  if (t < NBUK) {
    int base = sm[t] - v;   // exclusive
    bukbase[t] = base;
    bukcur[t] = base;
  }
  if (t == 0) { bukbase[NBUK] = ET; off[N] = ET; }
}

// Pass B: scatter packed (src,dstlow) into bucket-major storage; per-block
// contiguous runs reserved with one global atomic per touched bucket.
__global__ __launch_bounds__(256) void k_scatter(const int* __restrict__ ei, int E, int N,
                                                 int* __restrict__ bukcur,
                                                 int* __restrict__ pairs) {
  __shared__ int hist[MAXBUK];
  int t = threadIdx.x;
  hist[t] = 0; hist[t + 256] = 0;
  __syncthreads();
  long long e0 = (long long)blockIdx.x * CHUNK;
  int ET = E + N;
  int myP[16], myB[16];
#pragma unroll
  for (int i = 0; i < 16; ++i) {
    long long e = e0 + i * 256 + t;
    if (e < ET) {
      int s = e < E ? ei[e] : (int)(e - E);
      int d = e < E ? ei[E + e] : (int)(e - E);
      myP[i] = s | ((d & (BW - 1)) << 20);
      myB[i] = d >> BWL;
      atomicAdd(&hist[myB[i]], 1);
    } else {
      myB[i] = -1;
    }
  }
  __syncthreads();
  // reserve a contiguous run per bucket; hist becomes the LDS write cursor
  for (int b = t; b < MAXBUK; b += 256) {
    int c = hist[b];
    hist[b] = c ? atomicAdd(&bukcur[b], c) : 0;
  }
  __syncthreads();
#pragma unroll
  for (int i = 0; i < 16; ++i) {
    if (myB[i] >= 0) {
      int pos = atomicAdd(&hist[myB[i]], 1);
      pairs[pos] = myP[i];
    }
  }
}

// Pass C: per-bucket fine CSR: LDS count over 128 dsts, scan, write off[] and csr[].
__global__ __launch_bounds__(256) void k_csr(const int* __restrict__ pairs,
                                             const int* __restrict__ bukbase,
                                             int* __restrict__ off, int* __restrict__ csr,
                                             int N) {
  __shared__ int cnt[BW];
  __shared__ int cur[BW];
  int b = blockIdx.x, t = threadIdx.x;
  int beg = bukbase[b], end = bukbase[b + 1];
  if (t < BW) cnt[t] = 0;
  __syncthreads();
  for (int j = beg + t; j < end; j += 256)
    atomicAdd(&cnt[(pairs[j] >> 20) & (BW - 1)], 1);
  __syncthreads();
  int my = t < BW ? cnt[t] : 0;
  for (int o = 1; o < BW; o <<= 1) {
    int v = (t < BW && t >= o) ? cnt[t - o] : 0;
    __syncthreads();
    if (t < BW) cnt[t] += v;
    __syncthreads();
  }
  if (t < BW) {
    int start = beg + cnt[t] - my;   // exclusive within bucket
    cur[t] = start;
    int d0 = b * BW + t;
    if (d0 < N) off[d0] = start;
  }
  __syncthreads();
  for (int j = beg + t; j < end; j += 256) {
    int pr = pairs[j];
    int pos = atomicAdd(&cur[(pr >> 20) & (BW - 1)], 1);
    csr[pos] = pr & 0xFFFFF;
  }
}

// ---------------- layer 1 GEMM ----------------
// 64 rows x 128 cols per block; 256 threads; thread owns 8 rows x 4 cols.
__global__ __launch_bounds__(256) void k_gemm1(
    const float* __restrict__ x, const float* __restrict__ W1,
    const float* __restrict__ as, const float* __restrict__ ad,
    uint* __restrict__ h1b, float* __restrict__ a_src,
    float* __restrict__ a_dst, int N) {
  __shared__ float xs[F1 * XS_STRIDE];   // xs[k][row], 34 KB
  int tx = threadIdx.x;
  int cg = tx & 31;          // col group: cols 4cg..4cg+3
  int rg = tx >> 5;          // row group: rows 8rg..8rg+7
  int r0 = blockIdx.x * 64;

  {
    int row = tx & 63, kq0 = tx >> 6;   // kq0 in [0,4)
#pragma unroll
    for (int it = 0; it < 8; ++it) {
      int k4 = (it * 4 + kq0) * 4;
      float4 v = make_float4(0.f, 0.f, 0.f, 0.f);
      if (r0 + row < N) v = *reinterpret_cast<const float4*>(&x[(size_t)(r0 + row) * F1 + k4]);
      xs[(k4 + 0) * XS_STRIDE + row] = v.x;
      xs[(k4 + 1) * XS_STRIDE + row] = v.y;
      xs[(k4 + 2) * XS_STRIDE + row] = v.z;
      xs[(k4 + 3) * XS_STRIDE + row] = v.w;
    }
  }
  __syncthreads();

  float acc[8][4];
#pragma unroll
  for (int i = 0; i < 8; ++i)
#pragma unroll
    for (int j = 0; j < 4; ++j) acc[i][j] = 0.f;

#pragma unroll 4
  for (int k = 0; k < F1; ++k) {
    float4 w = *reinterpret_cast<const float4*>(&W1[k * F1 + 4 * cg]);
    float4 xa = *reinterpret_cast<const float4*>(&xs[k * XS_STRIDE + rg * 8]);
    float4 xb = *reinterpret_cast<const float4*>(&xs[k * XS_STRIDE + rg * 8 + 4]);
    const float xr[8] = {xa.x, xa.y, xa.z, xa.w, xb.x, xb.y, xb.z, xb.w};
#pragma unroll
    for (int i = 0; i < 8; ++i) {
      acc[i][0] = fmaf(xr[i], w.x, acc[i][0]);
      acc[i][1] = fmaf(xr[i], w.y, acc[i][1]);
      acc[i][2] = fmaf(xr[i], w.z, acc[i][2]);
      acc[i][3] = fmaf(xr[i], w.w, acc[i][3]);
    }
  }

  float4 as4 = *reinterpret_cast<const float4*>(&as[4 * cg]);
  float4 ad4 = *reinterpret_cast<const float4*>(&ad[4 * cg]);
  int h = cg >> 2;
#pragma unroll
  for (int i = 0; i < 8; ++i) {
    int row = r0 + rg * 8 + i;
    bool act = row < N;
    if (act) {
      uint2 pk;
      pk.x = (uint)f2bf(acc[i][0]) | ((uint)f2bf(acc[i][1]) << 16);
      pk.y = (uint)f2bf(acc[i][2]) | ((uint)f2bf(acc[i][3]) << 16);
      *reinterpret_cast<uint2*>(&h1b[(size_t)row * 64 + 2 * cg]) = pk;
    }
    float ps = acc[i][0] * as4.x + acc[i][1] * as4.y + acc[i][2] * as4.z + acc[i][3] * as4.w;
    float pd = acc[i][0] * ad4.x + acc[i][1] * ad4.y + acc[i][2] * ad4.z + acc[i][3] * ad4.w;
    ps += __shfl_xor(ps, 1); ps += __shfl_xor(ps, 2);
    pd += __shfl_xor(pd, 1); pd += __shfl_xor(pd, 2);
    if (act && (cg & 3) == 0) {
      a_src[row * HEADS + h] = ps;
      a_dst[row * HEADS + h] = pd;
    }
  }
}

// ---------------- layer 1 aggregate ----------------
// 1 wave/dst; two 32-lane halves process alternating edges; lane owns 4
// channels via uint2 (8B) loads; halves combined with shfl_xor(32).
__global__ void k_agg1(const int* __restrict__ off, const int* __restrict__ csr,
                       const uint2* __restrict__ h1b2, const float* __restrict__ a_src,
                       const float* __restrict__ a_dst, const float* __restrict__ b1,
                       float* __restrict__ out1, int N) {
  int w = threadIdx.x >> 6, lane = threadIdx.x & 63;
  int half = lane >> 5, c2 = lane & 31, h = c2 >> 2;   // channels 4c2..4c2+3
  int d = blockIdx.x * 4 + w;
  if (d >= N) return;
  int beg = off[d], end = off[d + 1];
  float adl = a_dst[d * HEADS + h];
  float a0 = 0.f, a1 = 0.f, a2 = 0.f, a3 = 0.f, den = 0.f;
#pragma unroll 2
  for (int j = beg + half; j < end; j += 2) {
    int s = csr[j];
    float v = a_src[s * HEADS + h] + adl;
    v = v >= 0.f ? v : 0.2f * v;
    float p = __expf(v);
    uint2 wd = h1b2[(size_t)s * 32 + c2];
    a0 = fmaf(p, bf2f_lo(wd.x), a0);
    a1 = fmaf(p, bf2f_hi(wd.x), a1);
    a2 = fmaf(p, bf2f_lo(wd.y), a2);
    a3 = fmaf(p, bf2f_hi(wd.y), a3);
    den += p;
  }
  a0 += __shfl_xor(a0, 32);
  a1 += __shfl_xor(a1, 32);
  a2 += __shfl_xor(a2, 32);
  a3 += __shfl_xor(a3, 32);
  den += __shfl_xor(den, 32);
  if (half == 0) {
    float inv = 1.f / den;   // self-loop guarantees den > 0
    float4 bb = *reinterpret_cast<const float4*>(&b1[4 * c2]);
    float4 o;
    o.x = a0 * inv + bb.x;
    o.y = a1 * inv + bb.y;
    o.z = a2 * inv + bb.z;
    o.w = a3 * inv + bb.w;
    *reinterpret_cast<float4*>(&out1[(size_t)d * F1 + 4 * c2]) = o;
  }
}

// ---------------- layer 2 GEMM ----------------
__global__ __launch_bounds__(256) void k_gemm2(
    const float* __restrict__ out1, const float* __restrict__ W2,
    const float* __restrict__ as2, const float* __restrict__ ad2,
    uint* __restrict__ h2b, float* __restrict__ a_src2,
    float* __restrict__ a_dst2, int N) {
  __shared__ float xs[F1 * XS_STRIDE];   // xs[k][row]
  int tx = threadIdx.x;
  int cg = tx & 15;          // cols 4cg..4cg+3
  int rg = tx >> 4;          // rows 4rg..4rg+3
  int r0 = blockIdx.x * 64;

  {
    int row = tx & 63, kq0 = tx >> 6;
#pragma unroll
    for (int it = 0; it < 8; ++it) {
      int k4 = (it * 4 + kq0) * 4;
      float4 v = make_float4(0.f, 0.f, 0.f, 0.f);
      if (r0 + row < N) v = *reinterpret_cast<const float4*>(&out1[(size_t)(r0 + row) * F1 + k4]);
      v.x = v.x > 0.f ? v.x : __expf(v.x) - 1.f;
      v.y = v.y > 0.f ? v.y : __expf(v.y) - 1.f;
      v.z = v.z > 0.f ? v.z : __expf(v.z) - 1.f;
      v.w = v.w > 0.f ? v.w : __expf(v.w) - 1.f;
      xs[(k4 + 0) * XS_STRIDE + row] = v.x;
      xs[(k4 + 1) * XS_STRIDE + row] = v.y;
      xs[(k4 + 2) * XS_STRIDE + row] = v.z;
      xs[(k4 + 3) * XS_STRIDE + row] = v.w;
    }
  }
  __syncthreads();

  float acc[4][4];
#pragma unroll
  for (int i = 0; i < 4; ++i)
#pragma unroll
    for (int j = 0; j < 4; ++j) acc[i][j] = 0.f;

#pragma unroll 4
  for (int k = 0; k < F1; ++k) {
    float4 w = *reinterpret_cast<const float4*>(&W2[k * OUTD + 4 * cg]);
    float4 xa = *reinterpret_cast<const float4*>(&xs[k * XS_STRIDE + rg * 4]);
    const float xr[4] = {xa.x, xa.y, xa.z, xa.w};
#pragma unroll
    for (int i = 0; i < 4; ++i) {
      acc[i][0] = fmaf(xr[i], w.x, acc[i][0]);
      acc[i][1] = fmaf(xr[i], w.y, acc[i][1]);
      acc[i][2] = fmaf(xr[i], w.z, acc[i][2]);
      acc[i][3] = fmaf(xr[i], w.w, acc[i][3]);
    }
  }

  float4 as4 = *reinterpret_cast<const float4*>(&as2[4 * cg]);
  float4 ad4 = *reinterpret_cast<const float4*>(&ad2[4 * cg]);
#pragma unroll
  for (int i = 0; i < 4; ++i) {
    int row = r0 + rg * 4 + i;
    bool act = row < N;
    if (act) {
      uint2 pk;
      pk.x = (uint)f2bf(acc[i][0]) | ((uint)f2bf(acc[i][1]) << 16);
      pk.y = (uint)f2bf(acc[i][2]) | ((uint)f2bf(acc[i][3]) << 16);
      *reinterpret_cast<uint2*>(&h2b[(size_t)row * 32 + 2 * cg]) = pk;
    }
    float ps = acc[i][0] * as4.x + acc[i][1] * as4.y + acc[i][2] * as4.z + acc[i][3] * as4.w;
    float pd = acc[i][0] * ad4.x + acc[i][1] * ad4.y + acc[i][2] * ad4.z + acc[i][3] * ad4.w;
    ps += __shfl_xor(ps, 1); ps += __shfl_xor(ps, 2);
    ps += __shfl_xor(ps, 4); ps += __shfl_xor(ps, 8);
    pd += __shfl_xor(pd, 1); pd += __shfl_xor(pd, 2);
    pd += __shfl_xor(pd, 4); pd += __shfl_xor(pd, 8);
    if (act && cg == 0) {
      a_src2[row] = ps;
      a_dst2[row] = pd;
    }
  }
}

// ---------------- layer 2 aggregate ----------------
// 1 wave/dst; four 16-lane quarters process alternating edges; lane owns 4
// channels via uint2 loads; quarters combined with shfl_xor(16/32).
__global__ void k_agg2(const int* __restrict__ off, const int* __restrict__ csr,
                       const uint2* __restrict__ h2b2, const float* __restrict__ a_src2,
                       const float* __restrict__ a_dst2, const float* __restrict__ b2,
                       float* __restrict__ out, int N) {
  int w = threadIdx.x >> 6, lane = threadIdx.x & 63;
  int q = lane >> 4, c2 = lane & 15;   // channels 4c2..4c2+3
  int d = blockIdx.x * 4 + w;
  if (d >= N) return;
  int beg = off[d], end = off[d + 1];
  float adl = a_dst2[d];
  float a0 = 0.f, a1 = 0.f, a2 = 0.f, a3 = 0.f, den = 0.f;
#pragma unroll 2
  for (int j = beg + q; j < end; j += 4) {
    int s = csr[j];
    float v = a_src2[s] + adl;
    v = v >= 0.f ? v : 0.2f * v;
    float p = __expf(v);
    uint2 wd = h2b2[(size_t)s * 16 + c2];
    a0 = fmaf(p, bf2f_lo(wd.x), a0);
    a1 = fmaf(p, bf2f_hi(wd.x), a1);
    a2 = fmaf(p, bf2f_lo(wd.y), a2);
    a3 = fmaf(p, bf2f_hi(wd.y), a3);
    den += p;
  }
  a0 += __shfl_xor(a0, 16); a0 += __shfl_xor(a0, 32);
  a1 += __shfl_xor(a1, 16); a1 += __shfl_xor(a1, 32);
  a2 += __shfl_xor(a2, 16); a2 += __shfl_xor(a2, 32);
  a3 += __shfl_xor(a3, 16); a3 += __shfl_xor(a3, 32);
  den += __shfl_xor(den, 16); den += __shfl_xor(den, 32);
  if (q == 0) {
    float inv = 1.f / den;
    float4 bb = *reinterpret_cast<const float4*>(&b2[4 * c2]);
    float4 o;
    o.x = a0 * inv + bb.x;
    o.y = a1 * inv + bb.y;
    o.z = a2 * inv + bb.z;
    o.w = a3 * inv + bb.w;
    *reinterpret_cast<float4*>(&out[(size_t)d * OUTD + 4 * c2]) = o;
  }
}

extern "C" void kernel_launch(void* const* d_in, const int* in_sizes, int n_in,
                              void* d_out, int out_size, void* d_ws, size_t ws_size,
                              hipStream_t stream) {
  const float* x   = (const float*)d_in[0];
  const int*   ei  = (const int*)d_in[1];
  const float* W1  = (const float*)d_in[2];
  const float* as1 = (const float*)d_in[3];
  const float* ad1 = (const float*)d_in[4];
  const float* b1  = (const float*)d_in[5];
  const float* W2  = (const float*)d_in[6];
  const float* as2 = (const float*)d_in[7];
  const float* ad2 = (const float*)d_in[8];
  const float* b2  = (const float*)d_in[9];
  float* out = (float*)d_out;

  int N = in_sizes[0] / F1;
  int E = in_sizes[1] / 2;
  int ET = E + N;
  int NBUK = (N + BW - 1) / BW;       // 391 for N=50000 (<= MAXBUK)
  int NCH = (ET + CHUNK - 1) / CHUNK; // count/scatter blocks
  int NT = (N + 63) / 64;             // GEMM tiles

  // workspace layout (16B-aligned chunks)
  char* p = (char*)d_ws;
  auto alloc = [&](size_t bytes) {
    char* q = p;
    p += (bytes + 15) & ~(size_t)15;
    return q;
  };
  int* bukcnt  = (int*)alloc((size_t)NBUK * 4);
  int* bukbase = (int*)alloc((size_t)(NBUK + 1) * 4);
  int* bukcur  = (int*)alloc((size_t)NBUK * 4);
  int* off     = (int*)alloc((size_t)(N + 1) * 4);
  int* pairs   = (int*)alloc((size_t)ET * 4);
  int* csr     = (int*)alloc((size_t)ET * 4);
  uint* h1b    = (uint*)alloc((size_t)N * 64 * 4);
  float* out1  = (float*)alloc((size_t)N * F1 * 4);
  float* a_src1 = (float*)alloc((size_t)N * HEADS * 4);
  float* a_dst1 = (float*)alloc((size_t)N * HEADS * 4);
  // layer-2 aliases over dead layer-1 regions
  uint* h2b     = h1b;              // N*32 uint (h1b dead after k_agg1)
  float* a_src2 = a_src1;           // N
  float* a_dst2 = a_dst1;           // N

  // CSR build (shared by both layers)
  hipLaunchKernelGGL(k_z, dim3((NBUK + 255) / 256), dim3(256), 0, stream, bukcnt, NBUK);
  hipLaunchKernelGGL(k_bukcount, dim3(NCH), dim3(256), 0, stream, ei, E, N, bukcnt);
  hipLaunchKernelGGL(k_bukscan, dim3(1), dim3(512), 0, stream,
                     bukcnt, bukbase, bukcur, off, NBUK, N, ET);
  hipLaunchKernelGGL(k_scatter, dim3(NCH), dim3(256), 0, stream, ei, E, N, bukcur, pairs);
  hipLaunchKernelGGL(k_csr, dim3(NBUK), dim3(256), 0, stream, pairs, bukbase, off, csr, N);

  // layer 1
  hipLaunchKernelGGL(k_gemm1, dim3(NT), dim3(256), 0, stream,
                     x, W1, as1, ad1, h1b, a_src1, a_dst1, N);
  hipLaunchKernelGGL(k_agg1, dim3((N + 3) / 4), dim3(256), 0, stream,
                     off, csr, (const uint2*)h1b, a_src1, a_dst1, b1, out1, N);

  // layer 2
  hipLaunchKernelGGL(k_gemm2, dim3(NT), dim3(256), 0, stream,
                     out1, W2, as2, ad2, h2b, a_src2, a_dst2, N);
  hipLaunchKernelGGL(k_agg2, dim3((N + 3) / 4), dim3(256), 0, stream,
                     off, csr, (const uint2*)h2b, a_src2, a_dst2, b2, out, N);
}